// Round 15
// baseline (253.397 us; speedup 1.0000x reference)
//
#include <hip/hip_runtime.h>
#include <hip/hip_bf16.h>
#include <math.h>

// ---- problem constants ----
#define B_ 2
#define L_ 1024
#define HID_ 1536
#define NH_ 24
#define HD_ 64
#define DSSM_ 1536
#define QKV_ 4608
#define M_ 2048

typedef __attribute__((ext_vector_type(8))) short short8;
typedef __attribute__((ext_vector_type(4))) short short4e;
typedef __attribute__((ext_vector_type(4))) float floatx4;

// async global -> LDS, 16 bytes per lane (global_load_lds_dwordx4)
__device__ __forceinline__ void gload_lds16(const short* g, short* l)
{
    __builtin_amdgcn_global_load_lds(
        (const __attribute__((address_space(1))) void*)g,
        (__attribute__((address_space(3))) void*)l,
        16, 0, 0);
}

__device__ __forceinline__ float bfs2f(short s)
{
    unsigned u = ((unsigned)(unsigned short)s) << 16;
    float f; __builtin_memcpy(&f, &u, 4); return f;
}
__device__ __forceinline__ short f2bfs(float f)
{
    __hip_bfloat16 h = __float2bfloat16(f);
    short s; __builtin_memcpy(&s, &h, 2); return s;
}

// 128-row i-tile slice tables: 15 slices per (b,nh)
__device__ const int pIt[15] = {0,1,2,3,3,4,4,5,5,6,6,6,7,7,7};
__device__ const int pJ0[15] = {0,0,0,0,6,0,6,0,6,0,6,12,0,6,12};
__device__ const int pSl[15] = {0,0,0,0,1,0,1,0,1,0,1,2,0,1,2};

#define CN1 (QKV_ * HID_)     // 7,077,888
#define CN2 (DSSM_ * HID_)    // 2,359,296
#define CN3 (HID_ * DSSM_)    // 2,359,296

#define MFMA_ __builtin_amdgcn_mfma_f32_16x16x32_bf16
#define BAR_() __builtin_amdgcn_s_barrier()
#define SCHED_ __builtin_amdgcn_sched_barrier(0)

// =====================================================================
// weights cast (low-VGPR streaming kernel — kept SEPARATE from dtproj)
// =====================================================================
__global__ void cast_w_kernel(
    const float* __restrict__ wq,
    const float* __restrict__ wz, const float* __restrict__ wo,
    __hip_bfloat16* __restrict__ wcat,   // [QKV+DSSM, HID]
    __hip_bfloat16* __restrict__ wob)
{
    int i = (blockIdx.x * 256 + threadIdx.x) * 4;
    const float* src; __hip_bfloat16* dst; int off;
    if (i < CN1)             { src = wq; dst = wcat;       off = i; }
    else if (i < CN1 + CN2)  { src = wz; dst = wcat + CN1; off = i - CN1; }
    else                     { src = wo; dst = wob;        off = i - CN1 - CN2; }
    float4 f = *reinterpret_cast<const float4*>(src + off);
    dst[off]     = __float2bfloat16(f.x);
    dst[off + 1] = __float2bfloat16(f.y);
    dst[off + 2] = __float2bfloat16(f.z);
    dst[off + 3] = __float2bfloat16(f.w);
}

// =====================================================================
// dt projection + folded x->bf16 cast (256 blocks, high VGPR ok here)
// =====================================================================
__global__ __launch_bounds__(256) void dtproj_kernel(
    const float* __restrict__ x,        // [B*L, HID]
    const float* __restrict__ w_dt,     // [NH, HID]
    const float* __restrict__ dt_bias,  // [NH]
    const float* __restrict__ a_log,    // [NH]
    float* __restrict__ dt,             // [B*NH, L]
    float* __restrict__ dA,
    __hip_bfloat16* __restrict__ xb)    // [B*L, HID] bf16
{
    const int tid  = threadIdx.x;
    const int wave = tid >> 6;
    const int lane = tid & 63;
    const int m0   = blockIdx.x * 8 + wave * 2;   // rows m0, m0+1

    float4 xa[2][6];
#pragma unroll
    for (int rr = 0; rr < 2; ++rr)
#pragma unroll
        for (int j = 0; j < 6; ++j)
            xa[rr][j] = *reinterpret_cast<const float4*>(
                x + (size_t)(m0 + rr) * HID_ + lane * 4 + j * 256);

    short* xbp = reinterpret_cast<short*>(xb);
#pragma unroll
    for (int rr = 0; rr < 2; ++rr)
#pragma unroll
        for (int j = 0; j < 6; ++j) {
            short4e ov;
            ov[0] = f2bfs(xa[rr][j].x); ov[1] = f2bfs(xa[rr][j].y);
            ov[2] = f2bfs(xa[rr][j].z); ov[3] = f2bfs(xa[rr][j].w);
            *reinterpret_cast<short4e*>(
                xbp + (size_t)(m0 + rr) * HID_ + lane * 4 + j * 256) = ov;
        }

    float acc0[NH_], acc1[NH_];
#pragma unroll
    for (int n = 0; n < NH_; ++n) {
        float s0 = 0.f, s1 = 0.f;
#pragma unroll
        for (int j = 0; j < 6; ++j) {
            float4 w = *reinterpret_cast<const float4*>(
                w_dt + (size_t)n * HID_ + lane * 4 + j * 256);
            s0 += xa[0][j].x * w.x + xa[0][j].y * w.y
                + xa[0][j].z * w.z + xa[0][j].w * w.w;
            s1 += xa[1][j].x * w.x + xa[1][j].y * w.y
                + xa[1][j].z * w.z + xa[1][j].w * w.w;
        }
        acc0[n] = s0;
        acc1[n] = s1;
    }

#pragma unroll
    for (int off = 32; off; off >>= 1) {
#pragma unroll
        for (int n = 0; n < NH_; ++n) {
            acc0[n] += __shfl_xor(acc0[n], off, 64);
            acc1[n] += __shfl_xor(acc1[n], off, 64);
        }
    }

    if (lane < NH_) {
        const int n = lane;
        float bias = dt_bias[n];
        float Aval = -__expf(a_log[n]);
        float v0 = acc0[n] + bias;
        float v1 = acc1[n] + bias;
        v0 = (v0 > 20.f) ? v0 : log1pf(__expf(v0));
        v1 = (v1 > 20.f) ? v1 : log1pf(__expf(v1));
        int b0 = m0 / L_, l0 = m0 % L_;
        size_t o0 = ((size_t)b0 * NH_ + n) * L_ + l0;
        dt[o0]     = v0;
        dA[o0]     = v0 * Aval;
        dt[o0 + 1] = v1;
        dA[o0 + 1] = v1 * Aval;
    }
}

// =====================================================================
// Fused qkv+z GEMM: 128x192 tile / BK=64 / 4 waves, 2 blocks/CU
// =====================================================================
#define CSTR 200   // epilogue C-LDS row stride (shorts): 400B, 16B-aligned

__global__ __launch_bounds__(256, 2) void gemm_qkvz_128(
    const __hip_bfloat16* __restrict__ A,
    const __hip_bfloat16* __restrict__ Bm,
    __hip_bfloat16* __restrict__ qkv_out,
    float* __restrict__ z_out,
    const float* __restrict__ b_z)
{
    extern __shared__ short lds[];
    const int K  = HID_;
    const int NT = K / 64;                 // 24 K-tiles
    const int tid   = threadIdx.x;
    const int lane  = tid & 63;
    const int wave  = tid >> 6;
    const int col16 = lane & 15;
    const int quad  = lane >> 4;
    const int wm = wave >> 1;              // 0..1  (M half, 64 rows)
    const int wn = wave & 1;               // 0..1  (N half, 96 cols)
    const int rowblk = blockIdx.y * 128;
    const int colblk = blockIdx.x * 192;

    const short* Ap = reinterpret_cast<const short*>(A);
    const short* Bp = reinterpret_cast<const short*>(Bm);

    const int o  = tid * 16;                         // byte off in 4KB unit
    const int s  = o ^ (((o >> 7) & 7) << 4);
    const int sr = s >> 7;                           // row 0..31 within unit
    const int sc = (s & 127) >> 1;                   // short col 0..63

    const int mask = (col16 & 7) << 4;
    const int e0 = ((quad * 16)      ^ mask) >> 1;   // kk=0
    const int e1 = ((64 + quad * 16) ^ mask) >> 1;   // kk=1
    const int arow = (wm * 64 + col16) * 64;         // + m*1024
    const int brow = (wn * 96 + col16) * 64;         // + n*1024

    floatx4 acc[4][6] = {};

    auto STAGE_ALL = [&](int c, int t) {   // 10 gload_lds: full tile t
        const short* ga = Ap + (size_t)(rowblk + sr) * K + t * 64 + sc;
        short* da = &lds[c * 8192 + tid * 8];
#pragma unroll
        for (int u = 0; u < 4; ++u)
            gload_lds16(ga + (size_t)(u * 32) * K, da + u * 2048);
        const short* gb = Bp + (size_t)(colblk + sr) * K + t * 64 + sc;
        short* db = &lds[16384 + c * 12288 + tid * 8];
#pragma unroll
        for (int u = 0; u < 6; ++u)
            gload_lds16(gb + (size_t)(u * 32) * K, db + u * 2048);
    };

    STAGE_ALL(0, 0);
    asm volatile("s_waitcnt vmcnt(0)" ::: "memory");
    SCHED_;
    BAR_();

    for (int t = 0; t < NT; ++t) {
        const int cur = t & 1;
        if (t + 1 < NT) STAGE_ALL(cur ^ 1, t + 1);

        const int Ab = cur * 8192;
        const int Bb = 16384 + cur * 12288;
        short8 af0[4], af1[4], bf0[6], bf1[6];
#pragma unroll
        for (int m = 0; m < 4; ++m) {
            af0[m] = *reinterpret_cast<const short8*>(&lds[Ab + arow + m * 1024 + e0]);
            af1[m] = *reinterpret_cast<const short8*>(&lds[Ab + arow + m * 1024 + e1]);
        }
#pragma unroll
        for (int n = 0; n < 6; ++n) {
            bf0[n] = *reinterpret_cast<const short8*>(&lds[Bb + brow + n * 1024 + e0]);
            bf1[n] = *reinterpret_cast<const short8*>(&lds[Bb + brow + n * 1024 + e1]);
        }
        asm volatile("s_waitcnt lgkmcnt(0)" ::: "memory");
        SCHED_;

        __builtin_amdgcn_s_setprio(1);
#pragma unroll
        for (int m = 0; m < 4; ++m)
#pragma unroll
            for (int n = 0; n < 6; ++n) {
                acc[m][n] = MFMA_(af0[m], bf0[n], acc[m][n], 0, 0, 0);
                acc[m][n] = MFMA_(af1[m], bf1[n], acc[m][n], 0, 0, 0);
            }
        __builtin_amdgcn_s_setprio(0);

        asm volatile("s_waitcnt vmcnt(0)" ::: "memory");
        SCHED_;
        BAR_();
    }

    // ---- epilogue ----
    if (blockIdx.x < 24) {
        const int rb = wm * 64 + quad * 4;
        const int cb = wn * 96 + col16;
#pragma unroll
        for (int m = 0; m < 4; ++m)
#pragma unroll
            for (int n = 0; n < 6; ++n)
#pragma unroll
                for (int r = 0; r < 4; ++r)
                    lds[(rb + m * 16 + r) * CSTR + cb + n * 16] =
                        f2bfs(acc[m][n][r]);
        __syncthreads();
        const int row = tid >> 1;          // 0..127
        const int seg = tid & 1;
        const short* srcp = &lds[row * CSTR + seg * 96];
        short* dstp = reinterpret_cast<short*>(qkv_out)
                    + (size_t)(rowblk + row) * QKV_ + colblk + seg * 96;
#pragma unroll
        for (int j = 0; j < 12; ++j)
            *reinterpret_cast<short8*>(dstp + j * 8) =
                *reinterpret_cast<const short8*>(srcp + j * 8);
    } else {
        const int row0  = rowblk + wm * 64;
        const int col0g = colblk + wn * 96 - QKV_;
#pragma unroll
        for (int m = 0; m < 4; ++m)
#pragma unroll
            for (int n = 0; n < 6; ++n)
#pragma unroll
                for (int r = 0; r < 4; ++r) {
                    int row = row0 + m * 16 + quad * 4 + r;
                    int col = col0g + n * 16 + col16;
                    z_out[(size_t)row * DSSM_ + col] = acc[m][n][r] + b_z[col];
                }
    }
}

// =====================================================================
// NT GEMM, LDS-staged (m97 structure) — output projection
// =====================================================================
template<int OUTMODE>
__global__ __launch_bounds__(256) void gemm_nt(
    const __hip_bfloat16* __restrict__ A,
    const __hip_bfloat16* __restrict__ Bm,
    void* __restrict__ Cv,
    const float* __restrict__ bias,
    int M, int N, int K)
{
    const int lane  = threadIdx.x & 63;
    const int wave  = threadIdx.x >> 6;
    const int col16 = lane & 15;
    const int quad  = lane >> 4;
    const int wr    = wave >> 1;
    const int wc    = wave & 1;
    const int rowblk = blockIdx.y * 128;
    const int colblk = blockIdx.x * 128;

    const short* Ap = reinterpret_cast<const short*>(A);
    const short* Bp = reinterpret_cast<const short*>(Bm);

    __shared__ alignas(16) short As[128 * 32];
    __shared__ alignas(16) short Bs[128 * 32];

    const int srow = lane >> 2;
    const int scol = (lane & 3) * 8;

    floatx4 acc[4][4] = {};

    for (int k0 = 0; k0 < K; k0 += 32) {
#pragma unroll
        for (int s2 = 0; s2 < 2; ++s2) {
            const int seg = wave * 2 + s2;
            gload_lds16(Ap + (size_t)(rowblk + seg * 16 + srow) * K + k0 + scol,
                        &As[seg * 512]);
            gload_lds16(Bp + (size_t)(colblk + seg * 16 + srow) * K + k0 + scol,
                        &Bs[seg * 512]);
        }
        __syncthreads();

        short8 af[4], bf[4];
#pragma unroll
        for (int t = 0; t < 4; ++t) {
            af[t] = *reinterpret_cast<const short8*>(
                &As[(wr * 64 + t * 16 + col16) * 32 + quad * 8]);
            bf[t] = *reinterpret_cast<const short8*>(
                &Bs[(wc * 64 + t * 16 + col16) * 32 + quad * 8]);
        }
#pragma unroll
        for (int mt = 0; mt < 4; ++mt)
#pragma unroll
            for (int nt = 0; nt < 4; ++nt)
                acc[mt][nt] = __builtin_amdgcn_mfma_f32_16x16x32_bf16(
                    af[mt], bf[nt], acc[mt][nt], 0, 0, 0);
        __syncthreads();
    }

    const int row0 = rowblk + wr * 64;
    const int col0 = colblk + wc * 64;
#pragma unroll
    for (int mt = 0; mt < 4; ++mt) {
#pragma unroll
        for (int nt = 0; nt < 4; ++nt) {
#pragma unroll
            for (int r = 0; r < 4; ++r) {
                int row = row0 + mt * 16 + quad * 4 + r;
                int col = col0 + nt * 16 + col16;
                float v = acc[mt][nt][r];
                if (OUTMODE == 1) v += bias[col];
                if (OUTMODE == 2)
                    ((__hip_bfloat16*)Cv)[(size_t)row * N + col] = __float2bfloat16(v);
                else
                    ((float*)Cv)[(size_t)row * N + col] = v;
            }
        }
    }
}

// =====================================================================
// conv+vdt+cumsum fused:
//   blocks [0,3072)      = q/k conv (8 ch/thread)
//   blocks [3072,3840)   = v conv + silu + v write + dt-scale + transpose
//   blocks [3840,3888)   = cumsum dA -> cs (one (b,nh) per block)
// =====================================================================
#define QK2 (2 * DSSM_)   // 3072

__global__ __launch_bounds__(256) void convvdt_kernel(
    const __hip_bfloat16* __restrict__ raw,
    const float* __restrict__ conv_w,
    const float* __restrict__ dt,           // [B*NH, L]
    const float* __restrict__ dA,           // [B*NH, L]
    __hip_bfloat16* __restrict__ q,
    __hip_bfloat16* __restrict__ k,
    __hip_bfloat16* __restrict__ v,
    __hip_bfloat16* __restrict__ vt,        // [B,NH,HD,L], dt-scaled
    float* __restrict__ cs)                 // [B*NH, L]
{
    __shared__ short T[64][72];
    __shared__ float red4[4];
    const int tid = threadIdx.x;

    if (blockIdx.x >= 3840) {
        // ---- part C: cumsum of dA row -> cs (256-thread scan, 4/thread)
        const int bnh  = blockIdx.x - 3840;          // 0..47
        const int lane = tid & 63;
        const int wave = tid >> 6;
        float4 dv = *reinterpret_cast<const float4*>(dA + (size_t)bnh * L_ + tid * 4);
        float s1 = dv.x + dv.y;
        float s2 = s1 + dv.z;
        float s3 = s2 + dv.w;
        float tot = s3;
        float sc = tot;
#pragma unroll
        for (int off = 1; off < 64; off <<= 1) {
            float o2 = __shfl_up(sc, off, 64);
            if (lane >= off) sc += o2;
        }
        if (lane == 63) red4[wave] = sc;
        __syncthreads();
        float woff = 0.f;
#pragma unroll
        for (int w = 0; w < 4; ++w)
            if (w < wave) woff += red4[w];
        float base = woff + sc - tot;
        float* dst = cs + (size_t)bnh * L_ + tid * 4;
        dst[0] = base + dv.x;
        dst[1] = base + s1;
        dst[2] = base + s2;
        dst[3] = base + s3;
        return;
    }

    if (blockIdx.x < 3072) {
        // ---- part A: q/k conv ----
        int idx8 = blockIdx.x * 256 + tid;          // over B*L*QK2/8
        int c8 = (idx8 % (QK2 / 8)) * 8;
        int ml = idx8 / (QK2 / 8);
        int l  = ml % L_;
        int b  = ml / L_;

        const short* base = reinterpret_cast<const short*>(raw) + (size_t)ml * QKV_ + c8;
        short8 curv = *reinterpret_cast<const short8*>(base);
        short8 prevv = {};
        if (l > 0) prevv = *reinterpret_cast<const short8*>(base - QKV_);

        float4 w0 = *reinterpret_cast<const float4*>(conv_w + c8 * 2);
        float4 w1 = *reinterpret_cast<const float4*>(conv_w + c8 * 2 + 4);
        float4 w2 = *reinterpret_cast<const float4*>(conv_w + c8 * 2 + 8);
        float4 w3 = *reinterpret_cast<const float4*>(conv_w + c8 * 2 + 12);
        const float wa[16] = {w0.x, w0.y, w0.z, w0.w, w1.x, w1.y, w1.z, w1.w,
                              w2.x, w2.y, w2.z, w2.w, w3.x, w3.y, w3.z, w3.w};

        short8 outv;
#pragma unroll
        for (int j = 0; j < 8; ++j) {
            float u = bfs2f(prevv[j]) * wa[2 * j] + bfs2f(curv[j]) * wa[2 * j + 1];
            u = fmaxf(u, -80.f);
            outv[j] = f2bfs(u / (1.f + __expf(-u)));
        }

        int part = c8 / DSSM_;
        int cc   = c8 % DSSM_;
        int nh   = cc >> 6;
        int d    = cc & 63;
        __hip_bfloat16* dst = (part == 0) ? q : k;
        *reinterpret_cast<short8*>(
            reinterpret_cast<short*>(dst) + (((size_t)b * NH_ + nh) * L_ + l) * HD_ + d)
            = outv;
        return;
    }

    // ---- part B: v conv + write v + transpose (dt-scaled) -> vt ----
    const int bid2 = blockIdx.x - 3072;             // 0..767
    const int lt0 = (bid2 & 15) * 64;
    const int nh  = (bid2 >> 4) % NH_;
    const int b   = bid2 / (16 * NH_);
    const int bnh = b * NH_ + nh;

    {
        int row = tid >> 2;                          // 0..63
        int cc  = (tid & 3) * 16;                    // 0,16,32,48
        int l   = lt0 + row;
        int cglob = QK2 + nh * 64 + cc;              // raw channel base
        const short* rp = reinterpret_cast<const short*>(raw)
                        + (size_t)(b * L_ + l) * QKV_ + cglob;
        short8 cur0 = *reinterpret_cast<const short8*>(rp);
        short8 cur1 = *reinterpret_cast<const short8*>(rp + 8);
        short8 pv0 = {}, pv1 = {};
        if (l > 0) {
            pv0 = *reinterpret_cast<const short8*>(rp - QKV_);
            pv1 = *reinterpret_cast<const short8*>(rp + 8 - QKV_);
        }
        float wa[32];
#pragma unroll
        for (int w4 = 0; w4 < 8; ++w4) {
            float4 wv = *reinterpret_cast<const float4*>(conv_w + cglob * 2 + w4 * 4);
            wa[w4 * 4]     = wv.x; wa[w4 * 4 + 1] = wv.y;
            wa[w4 * 4 + 2] = wv.z; wa[w4 * 4 + 3] = wv.w;
        }
        float dtr = dt[(size_t)bnh * L_ + l];

        short8 vo0, vo1;
#pragma unroll
        for (int j = 0; j < 8; ++j) {
            float u = bfs2f(pv0[j]) * wa[2 * j] + bfs2f(cur0[j]) * wa[2 * j + 1];
            u = fmaxf(u, -80.f);
            float sV = u / (1.f + __expf(-u));
            vo0[j] = f2bfs(sV);
            T[row][cc + j] = f2bfs(sV * dtr);

            float u2 = bfs2f(pv1[j]) * wa[16 + 2 * j] + bfs2f(cur1[j]) * wa[16 + 2 * j + 1];
            u2 = fmaxf(u2, -80.f);
            float sV2 = u2 / (1.f + __expf(-u2));
            vo1[j] = f2bfs(sV2);
            T[row][cc + 8 + j] = f2bfs(sV2 * dtr);
        }
        short* vp = reinterpret_cast<short*>(v)
                  + ((size_t)bnh * L_ + l) * HD_ + cc;
        *reinterpret_cast<short8*>(vp)     = vo0;
        *reinterpret_cast<short8*>(vp + 8) = vo1;
    }
    __syncthreads();
    {
        int d  = tid >> 2;
        int lc = (tid & 3) * 16;
        short8 o0, o1;
#pragma unroll
        for (int j = 0; j < 8; ++j) {
            o0[j] = T[lc + j][d];
            o1[j] = T[lc + 8 + j][d];
        }
        short* dst = reinterpret_cast<short*>(vt)
                   + ((size_t)bnh * HD_ + d) * L_ + lt0 + lc;
        *reinterpret_cast<short8*>(dst)     = o0;
        *reinterpret_cast<short8*>(dst + 8) = o1;
    }
}

// =====================================================================
// quadratic SSD attention v8 — round-14 body + 128-j K staging (steps
// and barriers halve; n64 is even for every slice so no partial stages)
// + V-load hoisting (subtile-A V issued BEFORE the K drain so V/K
// latencies overlap; subtile-B V flies under subtile-A compute).
// K LDS 16KB layout [ch-half][128 rows][32ch]; total LDS ~35.9KB.
// =====================================================================
__global__ __launch_bounds__(256) void attn_kernel(
    const __hip_bfloat16* __restrict__ q,   // [B,NH,L,HD]
    const __hip_bfloat16* __restrict__ k,   // [B,NH,L,HD]
    const __hip_bfloat16* __restrict__ vt,  // [B,NH,HD,L], dt-scaled
    const float* __restrict__ cs,           // [B,NH,L]
    float* __restrict__ p0,                 // [B,L,DSSM] partials
    float* __restrict__ p1,
    float* __restrict__ p2)
{
    // XCD-grouping decode: 720 = 90 x 8; 6 (b,nh) groups per XCD.
    const int bid  = blockIdx.x;
    const int xcd  = bid & 7;
    const int tq   = bid >> 3;              // 0..89
    const int g    = (tq / 15) * 8 + xcd;   // (b,nh) group 0..47, XCD-pinned
    const int pidx = tq % 15;               // slice 0..14
    const int it   = pIt[pidx];             // 128-row i-tile 0..7
    const int sl   = pSl[pidx];             // partial index 0..2
    const int jt_beg = pJ0[pidx];
    const int b    = g / NH_;
    const int nh   = g % NH_;
    const int tid  = threadIdx.x;
    const int lane = tid & 63;
    const int wave = tid >> 6;
    const int col  = lane & 15;
    const int quad = lane >> 4;
    const int bnh  = b * NH_ + nh;
    const int iw0  = it * 128 + wave * 16;        // group 0 rows
    const int iw1  = iw0 + 64;                    // group 1 rows

    float* pout = (sl == 0) ? p0 : ((sl == 1) ? p1 : p2);

    const short* qp  = reinterpret_cast<const short*>(q);
    const short* kp  = reinterpret_cast<const short*>(k);
    const short* vtp = reinterpret_cast<const short*>(vt);

    __shared__ alignas(16) short Ks[8192];              // 16KB: [half][128][32]
    __shared__ alignas(16) short Ps[4 * 2 * 16 * 72];   // per wave x group
    __shared__ float Cj[384];                           // slice j-window

    const int jbase = jt_beg * 64;
    const int jlim  = min(384, L_ - jbase);
    if (tid < (jlim >> 2))
        *reinterpret_cast<float4*>(&Cj[tid * 4]) =
            *reinterpret_cast<const float4*>(cs + (size_t)bnh * L_ + jbase + tid * 4);

    // Q fragments for both row groups
    const short* qrow0 = qp + ((size_t)bnh * L_ + iw0 + col) * HD_;
    const short* qrow1 = qp + ((size_t)bnh * L_ + iw1 + col) * HD_;
    short8 aq0_0 = *reinterpret_cast<const short8*>(qrow0 + quad * 8);
    short8 aq0_1 = *reinterpret_cast<const short8*>(qrow0 + 32 + quad * 8);
    short8 aq1_0 = *reinterpret_cast<const short8*>(qrow1 + quad * 8);
    short8 aq1_1 = *reinterpret_cast<const short8*>(qrow1 + 32 + quad * 8);

    float csr0[4], csr1[4];
#pragma unroll
    for (int r = 0; r < 4; ++r) {
        csr0[r] = cs[(size_t)bnh * L_ + iw0 + quad * 4 + r];
        csr1[r] = cs[(size_t)bnh * L_ + iw1 + quad * 4 + r];
    }

    // stage 128 K rows: per wave 32 rows x 64ch -> 4 gload_lds
    auto STAGE_K128 = [&](int t128) {
        const short* gk = kp + ((size_t)bnh * L_ + jbase + t128 * 128
                                + wave * 32 + (lane >> 2)) * HD_ + (lane & 3) * 8;
        gload_lds16(gk,                 &Ks[wave * 1024 + lane * 8]);
        gload_lds16(gk + 16 * HD_,      &Ks[wave * 1024 + 512 + lane * 8]);
        gload_lds16(gk + 32,            &Ks[4096 + wave * 1024 + lane * 8]);
        gload_lds16(gk + 16 * HD_ + 32, &Ks[4096 + wave * 1024 + 512 + lane * 8]);
    };

    const int jt_end = min(jt_beg + 5, 2 * it + 1);
    const int n128 = (jt_end - jt_beg + 1) >> 1;   // n64 always even

    STAGE_K128(0);

    floatx4 accO0[4] = {};
    floatx4 accO1[4] = {};

    // one 64-j subtile: QK^T + decay -> Ps, then PV.  h = 0/1 row-half.
    auto PROCESS = [&](int j0, int h, short8 (&bv)[2][4]) {
#pragma unroll
        for (int s = 0; s < 4; ++s) {
            int jsub = j0 + s * 16;
            short8 bk0 = *reinterpret_cast<const short8*>(
                &Ks[(h * 64 + s * 16 + col) * 32 + quad * 8]);
            short8 bk1 = *reinterpret_cast<const short8*>(
                &Ks[4096 + (h * 64 + s * 16 + col) * 32 + quad * 8]);
            int j = jsub + col;
            float csj = Cj[j - jbase];

            if (jsub <= iw0 + 15) {
                floatx4 sc = {};
                sc = __builtin_amdgcn_mfma_f32_16x16x32_bf16(aq0_0, bk0, sc, 0, 0, 0);
                sc = __builtin_amdgcn_mfma_f32_16x16x32_bf16(aq0_1, bk1, sc, 0, 0, 0);
#pragma unroll
                for (int r = 0; r < 4; ++r) {
                    int i = iw0 + quad * 4 + r;
                    float e = (j <= i) ? __expf(csr0[r] - csj) : 0.f;
                    Ps[wave * 2304 + (quad * 4 + r) * 72 + s * 16 + col] =
                        f2bfs(sc[r] * e);
                }
            } else if (j0 + (s >> 1) * 32 <= iw0 + 15) {
#pragma unroll
                for (int r = 0; r < 4; ++r)
                    Ps[wave * 2304 + (quad * 4 + r) * 72 + s * 16 + col] = 0;
            }

            if (jsub <= iw1 + 15) {
                floatx4 sc = {};
                sc = __builtin_amdgcn_mfma_f32_16x16x32_bf16(aq1_0, bk0, sc, 0, 0, 0);
                sc = __builtin_amdgcn_mfma_f32_16x16x32_bf16(aq1_1, bk1, sc, 0, 0, 0);
#pragma unroll
                for (int r = 0; r < 4; ++r) {
                    int i = iw1 + quad * 4 + r;
                    float e = (j <= i) ? __expf(csr1[r] - csj) : 0.f;
                    Ps[wave * 2304 + 1152 + (quad * 4 + r) * 72 + s * 16 + col] =
                        f2bfs(sc[r] * e);
                }
            } else if (j0 + (s >> 1) * 32 <= iw1 + 15) {
#pragma unroll
                for (int r = 0; r < 4; ++r)
                    Ps[wave * 2304 + 1152 + (quad * 4 + r) * 72 + s * 16 + col] = 0;
            }
        }

#pragma unroll
        for (int c = 0; c < 2; ++c) {
            if (j0 + c * 32 <= iw0 + 15) {
                short8 pa = *reinterpret_cast<const short8*>(
                    &Ps[wave * 2304 + col * 72 + c * 32 + quad * 8]);
#pragma unroll
                for (int nt = 0; nt < 4; ++nt)
                    accO0[nt] = __builtin_amdgcn_mfma_f32_16x16x32_bf16(
                        pa, bv[c][nt], accO0[nt], 0, 0, 0);
            }
            if (j0 + c * 32 <= iw1 + 15) {
                short8 pa = *reinterpret_cast<const short8*>(
                    &Ps[wave * 2304 + 1152 + col * 72 + c * 32 + quad * 8]);
#pragma unroll
                for (int nt = 0; nt < 4; ++nt)
                    accO1[nt] = __builtin_amdgcn_mfma_f32_16x16x32_bf16(
                        pa, bv[c][nt], accO1[nt], 0, 0, 0);
            }
        }
    };

    for (int t = 0; t < n128; ++t) {
        const int j0A = jbase + t * 128;
        const int j0B = j0A + 64;

        // hoist V(A) ABOVE the K drain: V/K latencies overlap
        short8 bvA[2][4];
#pragma unroll
        for (int c = 0; c < 2; ++c) {
            if (j0A + c * 32 <= iw1 + 15) {
#pragma unroll
                for (int nt = 0; nt < 4; ++nt)
                    bvA[c][nt] = *reinterpret_cast<const short8*>(
                        vtp + ((size_t)bnh * HD_ + nt * 16 + col) * L_
                            + j0A + c * 32 + quad * 8);
            }
        }

        asm volatile("s_waitcnt vmcnt(0)" ::: "memory");
        SCHED_;
        __syncthreads();                          // K 128-tile (and Cj) resident

        // V(B) in flight under subtile-A compute
        short8 bvB[2][4];
#pragma unroll
        for (int c = 0; c < 2; ++c) {
            if (j0B + c * 32 <= iw1 + 15) {
#pragma unroll
                for (int nt = 0; nt < 4; ++nt)
                    bvB[c][nt] = *reinterpret_cast<const short8*>(
                        vtp + ((size_t)bnh * HD_ + nt * 16 + col) * L_
                            + j0B + c * 32 + quad * 8);
            }
        }

        PROCESS(j0A, 0, bvA);
        PROCESS(j0B, 1, bvB);

        __syncthreads();                    // all waves done reading Ks
        if (t + 1 < n128) STAGE_K128(t + 1);
    }

#pragma unroll
    for (int nt = 0; nt < 4; ++nt) {
#pragma unroll
        for (int r = 0; r < 4; ++r) {
            int dv = nt * 16 + col;
            int i0 = iw0 + quad * 4 + r;
            int i1 = iw1 + quad * 4 + r;
            pout[((size_t)b * L_ + i0) * DSSM_ + nh * HD_ + dv] = accO0[nt][r];
            pout[((size_t)b * L_ + i1) * DSSM_ + nh * HD_ + dv] = accO1[nt][r];
        }
    }
}

// =====================================================================
// gate: (p0[+p1][+p2] + v*D) * silu(z), then RMSNorm * rms_w  -> bf16
// =====================================================================
__global__ __launch_bounds__(256) void gate_rms_kernel(
    const float* __restrict__ p0,
    const float* __restrict__ p1,
    const float* __restrict__ p2,
    const float* __restrict__ z,
    const __hip_bfloat16* __restrict__ v,   // [B,NH,L,HD]
    const float* __restrict__ Dm,           // [NH,HD]
    const float* __restrict__ rms_w,
    __hip_bfloat16* __restrict__ yn)
{
    int m   = blockIdx.x;           // b*L + l
    int b   = m / L_;
    int l   = m % L_;
    int tid = threadIdx.x;
    size_t base = (size_t)m * DSSM_;
    const bool has1 = (l >= 384);
    const bool has2 = (l >= 768);

    floatx4 acc4[2] = {};
    float ss = 0.f;
#pragma unroll
    for (int t = 0; t < 2; ++t) {
        int i4 = t * 256 + tid;
        if (i4 < DSSM_ / 4) {
            int c  = i4 * 4;
            int nh = c >> 6, d = c & 63;
            floatx4 p = *reinterpret_cast<const floatx4*>(p0 + base + c);
            if (has1) p += *reinterpret_cast<const floatx4*>(p1 + base + c);
            if (has2) p += *reinterpret_cast<const floatx4*>(p2 + base + c);
            floatx4 dm = *reinterpret_cast<const floatx4*>(Dm + c);
            floatx4 zz = *reinterpret_cast<const floatx4*>(z + base + c);
            short4e vv = *reinterpret_cast<const short4e*>(
                reinterpret_cast<const short*>(v)
                + (((size_t)b * NH_ + nh) * L_ + l) * HD_ + d);
            floatx4 g;
#pragma unroll
            for (int j = 0; j < 4; ++j) {
                float yv = p[j] + bfs2f(vv[j]) * dm[j];
                float zv = fmaxf(zz[j], -80.f);
                float gv = yv * (zv / (1.f + __expf(-zv)));
                ss += gv * gv;
                g[j] = gv;
            }
            acc4[t] = g;
        }
    }
#pragma unroll
    for (int off = 32; off; off >>= 1) ss += __shfl_xor(ss, off, 64);
    __shared__ float red[4];
    if ((tid & 63) == 0) red[tid >> 6] = ss;
    __syncthreads();
    ss = red[0] + red[1] + red[2] + red[3];
    float r = rsqrtf(ss / (float)DSSM_ + 1e-6f);
#pragma unroll
    for (int t = 0; t < 2; ++t) {
        int i4 = t * 256 + tid;
        if (i4 < DSSM_ / 4) {
            int c = i4 * 4;
            floatx4 rw = *reinterpret_cast<const floatx4*>(rms_w + c);
            short4e o;
#pragma unroll
            for (int j = 0; j < 4; ++j)
                o[j] = f2bfs(acc4[t][j] * r * rw[j]);
            *reinterpret_cast<short4e*>(
                reinterpret_cast<short*>(yn) + base + c) = o;
        }
    }
}

// =====================================================================
extern "C" void kernel_launch(void* const* d_in, const int* in_sizes, int n_in,
                              void* d_out, int out_size, void* d_ws, size_t ws_size,
                              hipStream_t stream)
{
    const float* x       = (const float*)d_in[0];
    const float* w_qkv   = (const float*)d_in[1];
    const float* conv_w  = (const float*)d_in[2];
    const float* w_dt    = (const float*)d_in[3];
    const float* dt_bias = (const float*)d_in[4];
    const float* a_log   = (const float*)d_in[5];
    const float* Dm      = (const float*)d_in[6];
    const float* w_z     = (const float*)d_in[7];
    const float* b_z     = (const float*)d_in[8];
    const float* rms_w   = (const float*)d_in[9];
    const float* w_o     = (const float*)d_in[10];
    float* out = (float*)d_out;

    char* ws = (char*)d_ws;

    // ---- workspace layout (bytes), total 80,805,888 — overlap-audited ----
    __hip_bfloat16* xb    = (__hip_bfloat16*)(ws);
    __hip_bfloat16* wob   = (__hip_bfloat16*)(ws + 6291456);
    float*          zbuf  = (float*)(ws + 11010048);
    __hip_bfloat16* wcat  = (__hip_bfloat16*)(ws + 23592960);
    __hip_bfloat16* qkvb  = (__hip_bfloat16*)(ws + 42467328);
    __hip_bfloat16* qb    = (__hip_bfloat16*)(ws + 61341696);
    __hip_bfloat16* kb    = (__hip_bfloat16*)(ws + 67633152);
    __hip_bfloat16* vb    = (__hip_bfloat16*)(ws + 73924608);
    float* dt   = (float*)(ws + 80216064);
    float* dA   = (float*)(ws + 80412672);
    float* cs   = (float*)(ws + 80609280);
    // aliases (lifetimes disjoint)
    __hip_bfloat16* vtb = (__hip_bfloat16*)(ws);   // over xb after gemm
    __hip_bfloat16* yn  = (__hip_bfloat16*)(ws);
    float* p0 = (float*)(ws + 23592960);
    float* p1 = (float*)(ws + 36175872);
    float* p2 = (float*)(ws + 48758784);

    // one-time: allow 81,920 B dynamic LDS for the 128x192 GEMM
    static bool attr_set = false;
    if (!attr_set) {
        (void)hipFuncSetAttribute(reinterpret_cast<const void*>(gemm_qkvz_128),
                                  hipFuncAttributeMaxDynamicSharedMemorySize,
                                  81920);
        attr_set = true;
    }

    // 1) weights cast (separate: low-VGPR streaming, full occupancy)
    cast_w_kernel<<<(CN1 + CN2 + CN3) / 1024, 256, 0, stream>>>(
        w_qkv, w_z, w_o, wcat, wob);

    // 2) dtproj + folded x->bf16 cast
    dtproj_kernel<<<M_ / 8, 256, 0, stream>>>(
        x, w_dt, dt_bias, a_log, dt, dA, xb);

    // 3) fused qkv+z GEMM  [2048 x 6144], 128x192 tile, 2 blocks/CU
    gemm_qkvz_128<<<dim3((QKV_ + DSSM_) / 192, M_ / 128), 256, 81920, stream>>>(
        xb, wcat, qkvb, zbuf, b_z);

    // 4) conv (q,k) + conv+transpose (v) + cumsum(dA->cs)
    convvdt_kernel<<<3888, 256, 0, stream>>>(
        qkvb, conv_w, dt, dA, qb, kb, vb, vtb, cs);

    // 5) attention (128-j steps, hoisted V) -> p0/p1/p2
    attn_kernel<<<720, 256, 0, stream>>>(
        qb, kb, vtb, cs, p0, p1, p2);

    // 6) gate + RMSNorm -> yn
    gate_rms_kernel<<<M_, 256, 0, stream>>>(p0, p1, p2, zbuf, vb, Dm, rms_w, yn);

    // 7) out = yn @ w_o^T
    gemm_nt<0><<<dim3(HID_ / 128, M_ / 128), 256, 0, stream>>>(
        yn, wob, (void*)out, nullptr, M_, HID_, DSSM_);
}

// Round 16
// 239.078 us; speedup vs baseline: 1.0599x; 1.0599x over previous
//
#include <hip/hip_runtime.h>
#include <hip/hip_bf16.h>
#include <math.h>

// ---- problem constants ----
#define B_ 2
#define L_ 1024
#define HID_ 1536
#define NH_ 24
#define HD_ 64
#define DSSM_ 1536
#define QKV_ 4608
#define M_ 2048

typedef __attribute__((ext_vector_type(8))) short short8;
typedef __attribute__((ext_vector_type(4))) short short4e;
typedef __attribute__((ext_vector_type(4))) float floatx4;

// async global -> LDS, 16 bytes per lane (global_load_lds_dwordx4)
__device__ __forceinline__ void gload_lds16(const short* g, short* l)
{
    __builtin_amdgcn_global_load_lds(
        (const __attribute__((address_space(1))) void*)g,
        (__attribute__((address_space(3))) void*)l,
        16, 0, 0);
}

__device__ __forceinline__ float bfs2f(short s)
{
    unsigned u = ((unsigned)(unsigned short)s) << 16;
    float f; __builtin_memcpy(&f, &u, 4); return f;
}
__device__ __forceinline__ short f2bfs(float f)
{
    __hip_bfloat16 h = __float2bfloat16(f);
    short s; __builtin_memcpy(&s, &h, 2); return s;
}

// 128-row i-tile slice tables: 15 slices per (b,nh)
__device__ const int pIt[15] = {0,1,2,3,3,4,4,5,5,6,6,6,7,7,7};
__device__ const int pJ0[15] = {0,0,0,0,6,0,6,0,6,0,6,12,0,6,12};
__device__ const int pSl[15] = {0,0,0,0,1,0,1,0,1,0,1,2,0,1,2};

#define CN1 (QKV_ * HID_)     // 7,077,888
#define CN2 (DSSM_ * HID_)    // 2,359,296
#define CN3 (HID_ * DSSM_)    // 2,359,296

#define MFMA_ __builtin_amdgcn_mfma_f32_16x16x32_bf16
#define BAR_() __builtin_amdgcn_s_barrier()
#define SCHED_ __builtin_amdgcn_sched_barrier(0)

// =====================================================================
// weights cast (low-VGPR streaming kernel — kept SEPARATE from dtproj)
// =====================================================================
__global__ void cast_w_kernel(
    const float* __restrict__ wq,
    const float* __restrict__ wz, const float* __restrict__ wo,
    __hip_bfloat16* __restrict__ wcat,   // [QKV+DSSM, HID]
    __hip_bfloat16* __restrict__ wob)
{
    int i = (blockIdx.x * 256 + threadIdx.x) * 4;
    const float* src; __hip_bfloat16* dst; int off;
    if (i < CN1)             { src = wq; dst = wcat;       off = i; }
    else if (i < CN1 + CN2)  { src = wz; dst = wcat + CN1; off = i - CN1; }
    else                     { src = wo; dst = wob;        off = i - CN1 - CN2; }
    float4 f = *reinterpret_cast<const float4*>(src + off);
    dst[off]     = __float2bfloat16(f.x);
    dst[off + 1] = __float2bfloat16(f.y);
    dst[off + 2] = __float2bfloat16(f.z);
    dst[off + 3] = __float2bfloat16(f.w);
}

// =====================================================================
// dt projection + folded x->bf16 cast (256 blocks, high VGPR ok here)
// =====================================================================
__global__ __launch_bounds__(256) void dtproj_kernel(
    const float* __restrict__ x,        // [B*L, HID]
    const float* __restrict__ w_dt,     // [NH, HID]
    const float* __restrict__ dt_bias,  // [NH]
    const float* __restrict__ a_log,    // [NH]
    float* __restrict__ dt,             // [B*NH, L]
    float* __restrict__ dA,
    __hip_bfloat16* __restrict__ xb)    // [B*L, HID] bf16
{
    const int tid  = threadIdx.x;
    const int wave = tid >> 6;
    const int lane = tid & 63;
    const int m0   = blockIdx.x * 8 + wave * 2;   // rows m0, m0+1

    float4 xa[2][6];
#pragma unroll
    for (int rr = 0; rr < 2; ++rr)
#pragma unroll
        for (int j = 0; j < 6; ++j)
            xa[rr][j] = *reinterpret_cast<const float4*>(
                x + (size_t)(m0 + rr) * HID_ + lane * 4 + j * 256);

    short* xbp = reinterpret_cast<short*>(xb);
#pragma unroll
    for (int rr = 0; rr < 2; ++rr)
#pragma unroll
        for (int j = 0; j < 6; ++j) {
            short4e ov;
            ov[0] = f2bfs(xa[rr][j].x); ov[1] = f2bfs(xa[rr][j].y);
            ov[2] = f2bfs(xa[rr][j].z); ov[3] = f2bfs(xa[rr][j].w);
            *reinterpret_cast<short4e*>(
                xbp + (size_t)(m0 + rr) * HID_ + lane * 4 + j * 256) = ov;
        }

    float acc0[NH_], acc1[NH_];
#pragma unroll
    for (int n = 0; n < NH_; ++n) {
        float s0 = 0.f, s1 = 0.f;
#pragma unroll
        for (int j = 0; j < 6; ++j) {
            float4 w = *reinterpret_cast<const float4*>(
                w_dt + (size_t)n * HID_ + lane * 4 + j * 256);
            s0 += xa[0][j].x * w.x + xa[0][j].y * w.y
                + xa[0][j].z * w.z + xa[0][j].w * w.w;
            s1 += xa[1][j].x * w.x + xa[1][j].y * w.y
                + xa[1][j].z * w.z + xa[1][j].w * w.w;
        }
        acc0[n] = s0;
        acc1[n] = s1;
    }

#pragma unroll
    for (int off = 32; off; off >>= 1) {
#pragma unroll
        for (int n = 0; n < NH_; ++n) {
            acc0[n] += __shfl_xor(acc0[n], off, 64);
            acc1[n] += __shfl_xor(acc1[n], off, 64);
        }
    }

    if (lane < NH_) {
        const int n = lane;
        float bias = dt_bias[n];
        float Aval = -__expf(a_log[n]);
        float v0 = acc0[n] + bias;
        float v1 = acc1[n] + bias;
        v0 = (v0 > 20.f) ? v0 : log1pf(__expf(v0));
        v1 = (v1 > 20.f) ? v1 : log1pf(__expf(v1));
        int b0 = m0 / L_, l0 = m0 % L_;
        size_t o0 = ((size_t)b0 * NH_ + n) * L_ + l0;
        dt[o0]     = v0;
        dA[o0]     = v0 * Aval;
        dt[o0 + 1] = v1;
        dA[o0 + 1] = v1 * Aval;
    }
}

// =====================================================================
// Fused qkv+z GEMM: 128x192 tile / BK=64 / 4 waves, 2 blocks/CU
// =====================================================================
#define CSTR 200   // epilogue C-LDS row stride (shorts): 400B, 16B-aligned

__global__ __launch_bounds__(256, 2) void gemm_qkvz_128(
    const __hip_bfloat16* __restrict__ A,
    const __hip_bfloat16* __restrict__ Bm,
    __hip_bfloat16* __restrict__ qkv_out,
    float* __restrict__ z_out,
    const float* __restrict__ b_z)
{
    extern __shared__ short lds[];
    const int K  = HID_;
    const int NT = K / 64;                 // 24 K-tiles
    const int tid   = threadIdx.x;
    const int lane  = tid & 63;
    const int wave  = tid >> 6;
    const int col16 = lane & 15;
    const int quad  = lane >> 4;
    const int wm = wave >> 1;              // 0..1  (M half, 64 rows)
    const int wn = wave & 1;               // 0..1  (N half, 96 cols)
    const int rowblk = blockIdx.y * 128;
    const int colblk = blockIdx.x * 192;

    const short* Ap = reinterpret_cast<const short*>(A);
    const short* Bp = reinterpret_cast<const short*>(Bm);

    const int o  = tid * 16;                         // byte off in 4KB unit
    const int s  = o ^ (((o >> 7) & 7) << 4);
    const int sr = s >> 7;                           // row 0..31 within unit
    const int sc = (s & 127) >> 1;                   // short col 0..63

    const int mask = (col16 & 7) << 4;
    const int e0 = ((quad * 16)      ^ mask) >> 1;   // kk=0
    const int e1 = ((64 + quad * 16) ^ mask) >> 1;   // kk=1
    const int arow = (wm * 64 + col16) * 64;         // + m*1024
    const int brow = (wn * 96 + col16) * 64;         // + n*1024

    floatx4 acc[4][6] = {};

    auto STAGE_ALL = [&](int c, int t) {   // 10 gload_lds: full tile t
        const short* ga = Ap + (size_t)(rowblk + sr) * K + t * 64 + sc;
        short* da = &lds[c * 8192 + tid * 8];
#pragma unroll
        for (int u = 0; u < 4; ++u)
            gload_lds16(ga + (size_t)(u * 32) * K, da + u * 2048);
        const short* gb = Bp + (size_t)(colblk + sr) * K + t * 64 + sc;
        short* db = &lds[16384 + c * 12288 + tid * 8];
#pragma unroll
        for (int u = 0; u < 6; ++u)
            gload_lds16(gb + (size_t)(u * 32) * K, db + u * 2048);
    };

    STAGE_ALL(0, 0);
    asm volatile("s_waitcnt vmcnt(0)" ::: "memory");
    SCHED_;
    BAR_();

    for (int t = 0; t < NT; ++t) {
        const int cur = t & 1;
        if (t + 1 < NT) STAGE_ALL(cur ^ 1, t + 1);

        const int Ab = cur * 8192;
        const int Bb = 16384 + cur * 12288;
        short8 af0[4], af1[4], bf0[6], bf1[6];
#pragma unroll
        for (int m = 0; m < 4; ++m) {
            af0[m] = *reinterpret_cast<const short8*>(&lds[Ab + arow + m * 1024 + e0]);
            af1[m] = *reinterpret_cast<const short8*>(&lds[Ab + arow + m * 1024 + e1]);
        }
#pragma unroll
        for (int n = 0; n < 6; ++n) {
            bf0[n] = *reinterpret_cast<const short8*>(&lds[Bb + brow + n * 1024 + e0]);
            bf1[n] = *reinterpret_cast<const short8*>(&lds[Bb + brow + n * 1024 + e1]);
        }
        asm volatile("s_waitcnt lgkmcnt(0)" ::: "memory");
        SCHED_;

        __builtin_amdgcn_s_setprio(1);
#pragma unroll
        for (int m = 0; m < 4; ++m)
#pragma unroll
            for (int n = 0; n < 6; ++n) {
                acc[m][n] = MFMA_(af0[m], bf0[n], acc[m][n], 0, 0, 0);
                acc[m][n] = MFMA_(af1[m], bf1[n], acc[m][n], 0, 0, 0);
            }
        __builtin_amdgcn_s_setprio(0);

        asm volatile("s_waitcnt vmcnt(0)" ::: "memory");
        SCHED_;
        BAR_();
    }

    // ---- epilogue ----
    if (blockIdx.x < 24) {
        const int rb = wm * 64 + quad * 4;
        const int cb = wn * 96 + col16;
#pragma unroll
        for (int m = 0; m < 4; ++m)
#pragma unroll
            for (int n = 0; n < 6; ++n)
#pragma unroll
                for (int r = 0; r < 4; ++r)
                    lds[(rb + m * 16 + r) * CSTR + cb + n * 16] =
                        f2bfs(acc[m][n][r]);
        __syncthreads();
        const int row = tid >> 1;          // 0..127
        const int seg = tid & 1;
        const short* srcp = &lds[row * CSTR + seg * 96];
        short* dstp = reinterpret_cast<short*>(qkv_out)
                    + (size_t)(rowblk + row) * QKV_ + colblk + seg * 96;
#pragma unroll
        for (int j = 0; j < 12; ++j)
            *reinterpret_cast<short8*>(dstp + j * 8) =
                *reinterpret_cast<const short8*>(srcp + j * 8);
    } else {
        const int row0  = rowblk + wm * 64;
        const int col0g = colblk + wn * 96 - QKV_;
#pragma unroll
        for (int m = 0; m < 4; ++m)
#pragma unroll
            for (int n = 0; n < 6; ++n)
#pragma unroll
                for (int r = 0; r < 4; ++r) {
                    int row = row0 + m * 16 + quad * 4 + r;
                    int col = col0g + n * 16 + col16;
                    z_out[(size_t)row * DSSM_ + col] = acc[m][n][r] + b_z[col];
                }
    }
}

// =====================================================================
// Output GEMM: out[M,HID] = yn[M,DSSM] @ wob[HID,DSSM]^T
// Dedicated 128x96 tile / BK=64 / 4 waves (2Mx2N, wave 64x48) — the
// proven qkvz-128 structure; grid 16x16 = 256 blocks (fills all CUs;
// the old m97 BK=32 version ran only 192 blocks = 25% idle chip).
// LDS 57,344 B (A dbuf 32KB + B dbuf 24KB).
// =====================================================================
__global__ __launch_bounds__(256, 2) void gemm_out_128(
    const __hip_bfloat16* __restrict__ A,
    const __hip_bfloat16* __restrict__ Bm,
    float* __restrict__ Co)
{
    extern __shared__ short lds[];
    const int K  = DSSM_;
    const int NT = K / 64;                 // 24 K-tiles
    const int tid   = threadIdx.x;
    const int lane  = tid & 63;
    const int wave  = tid >> 6;
    const int col16 = lane & 15;
    const int quad  = lane >> 4;
    const int wm = wave >> 1;              // 0..1  (M half, 64 rows)
    const int wn = wave & 1;               // 0..1  (N half, 48 cols)
    const int rowblk = blockIdx.y * 128;
    const int colblk = blockIdx.x * 96;

    const short* Ap = reinterpret_cast<const short*>(A);
    const short* Bp = reinterpret_cast<const short*>(Bm);

    const int o  = tid * 16;                         // byte off in 4KB unit
    const int s  = o ^ (((o >> 7) & 7) << 4);
    const int sr = s >> 7;                           // row 0..31 within unit
    const int sc = (s & 127) >> 1;                   // short col 0..63

    const int mask = (col16 & 7) << 4;
    const int e0 = ((quad * 16)      ^ mask) >> 1;   // kk=0
    const int e1 = ((64 + quad * 16) ^ mask) >> 1;   // kk=1
    const int arow = (wm * 64 + col16) * 64;         // + m*1024
    const int brow = (wn * 48 + col16) * 64;         // + n*1024

    floatx4 acc[4][3] = {};

    auto STAGE_ALL = [&](int c, int t) {   // 7 gload_lds: full tile t
        const short* ga = Ap + (size_t)(rowblk + sr) * K + t * 64 + sc;
        short* da = &lds[c * 8192 + tid * 8];
#pragma unroll
        for (int u = 0; u < 4; ++u)
            gload_lds16(ga + (size_t)(u * 32) * K, da + u * 2048);
        const short* gb = Bp + (size_t)(colblk + sr) * K + t * 64 + sc;
        short* db = &lds[16384 + c * 6144 + tid * 8];
#pragma unroll
        for (int u = 0; u < 3; ++u)
            gload_lds16(gb + (size_t)(u * 32) * K, db + u * 2048);
    };

    STAGE_ALL(0, 0);
    asm volatile("s_waitcnt vmcnt(0)" ::: "memory");
    SCHED_;
    BAR_();

    for (int t = 0; t < NT; ++t) {
        const int cur = t & 1;
        if (t + 1 < NT) STAGE_ALL(cur ^ 1, t + 1);

        const int Ab = cur * 8192;
        const int Bb = 16384 + cur * 6144;
        short8 af0[4], af1[4], bf0[3], bf1[3];
#pragma unroll
        for (int m = 0; m < 4; ++m) {
            af0[m] = *reinterpret_cast<const short8*>(&lds[Ab + arow + m * 1024 + e0]);
            af1[m] = *reinterpret_cast<const short8*>(&lds[Ab + arow + m * 1024 + e1]);
        }
#pragma unroll
        for (int n = 0; n < 3; ++n) {
            bf0[n] = *reinterpret_cast<const short8*>(&lds[Bb + brow + n * 1024 + e0]);
            bf1[n] = *reinterpret_cast<const short8*>(&lds[Bb + brow + n * 1024 + e1]);
        }
        asm volatile("s_waitcnt lgkmcnt(0)" ::: "memory");
        SCHED_;

        __builtin_amdgcn_s_setprio(1);
#pragma unroll
        for (int m = 0; m < 4; ++m)
#pragma unroll
            for (int n = 0; n < 3; ++n) {
                acc[m][n] = MFMA_(af0[m], bf0[n], acc[m][n], 0, 0, 0);
                acc[m][n] = MFMA_(af1[m], bf1[n], acc[m][n], 0, 0, 0);
            }
        __builtin_amdgcn_s_setprio(0);

        asm volatile("s_waitcnt vmcnt(0)" ::: "memory");
        SCHED_;
        BAR_();
    }

    // ---- epilogue: fp32 direct stores ----
    const int row0 = rowblk + wm * 64;
    const int col0 = colblk + wn * 48;
#pragma unroll
    for (int m = 0; m < 4; ++m)
#pragma unroll
        for (int n = 0; n < 3; ++n)
#pragma unroll
            for (int r = 0; r < 4; ++r) {
                int row = row0 + m * 16 + quad * 4 + r;
                int col = col0 + n * 16 + col16;
                Co[(size_t)row * HID_ + col] = acc[m][n][r];
            }
}

// =====================================================================
// conv+vdt+cumsum fused:
//   blocks [0,3072)      = q/k conv (8 ch/thread)
//   blocks [3072,3840)   = v conv + silu + v write + dt-scale + transpose
//   blocks [3840,3888)   = cumsum dA -> cs (one (b,nh) per block)
// =====================================================================
#define QK2 (2 * DSSM_)   // 3072

__global__ __launch_bounds__(256) void convvdt_kernel(
    const __hip_bfloat16* __restrict__ raw,
    const float* __restrict__ conv_w,
    const float* __restrict__ dt,           // [B*NH, L]
    const float* __restrict__ dA,           // [B*NH, L]
    __hip_bfloat16* __restrict__ q,
    __hip_bfloat16* __restrict__ k,
    __hip_bfloat16* __restrict__ v,
    __hip_bfloat16* __restrict__ vt,        // [B,NH,HD,L], dt-scaled
    float* __restrict__ cs)                 // [B*NH, L]
{
    __shared__ short T[64][72];
    __shared__ float red4[4];
    const int tid = threadIdx.x;

    if (blockIdx.x >= 3840) {
        // ---- part C: cumsum of dA row -> cs (256-thread scan, 4/thread)
        const int bnh  = blockIdx.x - 3840;          // 0..47
        const int lane = tid & 63;
        const int wave = tid >> 6;
        float4 dv = *reinterpret_cast<const float4*>(dA + (size_t)bnh * L_ + tid * 4);
        float s1 = dv.x + dv.y;
        float s2 = s1 + dv.z;
        float s3 = s2 + dv.w;
        float tot = s3;
        float sc = tot;
#pragma unroll
        for (int off = 1; off < 64; off <<= 1) {
            float o2 = __shfl_up(sc, off, 64);
            if (lane >= off) sc += o2;
        }
        if (lane == 63) red4[wave] = sc;
        __syncthreads();
        float woff = 0.f;
#pragma unroll
        for (int w = 0; w < 4; ++w)
            if (w < wave) woff += red4[w];
        float base = woff + sc - tot;
        float* dst = cs + (size_t)bnh * L_ + tid * 4;
        dst[0] = base + dv.x;
        dst[1] = base + s1;
        dst[2] = base + s2;
        dst[3] = base + s3;
        return;
    }

    if (blockIdx.x < 3072) {
        // ---- part A: q/k conv ----
        int idx8 = blockIdx.x * 256 + tid;          // over B*L*QK2/8
        int c8 = (idx8 % (QK2 / 8)) * 8;
        int ml = idx8 / (QK2 / 8);
        int l  = ml % L_;
        int b  = ml / L_;

        const short* base = reinterpret_cast<const short*>(raw) + (size_t)ml * QKV_ + c8;
        short8 curv = *reinterpret_cast<const short8*>(base);
        short8 prevv = {};
        if (l > 0) prevv = *reinterpret_cast<const short8*>(base - QKV_);

        float4 w0 = *reinterpret_cast<const float4*>(conv_w + c8 * 2);
        float4 w1 = *reinterpret_cast<const float4*>(conv_w + c8 * 2 + 4);
        float4 w2 = *reinterpret_cast<const float4*>(conv_w + c8 * 2 + 8);
        float4 w3 = *reinterpret_cast<const float4*>(conv_w + c8 * 2 + 12);
        const float wa[16] = {w0.x, w0.y, w0.z, w0.w, w1.x, w1.y, w1.z, w1.w,
                              w2.x, w2.y, w2.z, w2.w, w3.x, w3.y, w3.z, w3.w};

        short8 outv;
#pragma unroll
        for (int j = 0; j < 8; ++j) {
            float u = bfs2f(prevv[j]) * wa[2 * j] + bfs2f(curv[j]) * wa[2 * j + 1];
            u = fmaxf(u, -80.f);
            outv[j] = f2bfs(u / (1.f + __expf(-u)));
        }

        int part = c8 / DSSM_;
        int cc   = c8 % DSSM_;
        int nh   = cc >> 6;
        int d    = cc & 63;
        __hip_bfloat16* dst = (part == 0) ? q : k;
        *reinterpret_cast<short8*>(
            reinterpret_cast<short*>(dst) + (((size_t)b * NH_ + nh) * L_ + l) * HD_ + d)
            = outv;
        return;
    }

    // ---- part B: v conv + write v + transpose (dt-scaled) -> vt ----
    const int bid2 = blockIdx.x - 3072;             // 0..767
    const int lt0 = (bid2 & 15) * 64;
    const int nh  = (bid2 >> 4) % NH_;
    const int b   = bid2 / (16 * NH_);
    const int bnh = b * NH_ + nh;

    {
        int row = tid >> 2;                          // 0..63
        int cc  = (tid & 3) * 16;                    // 0,16,32,48
        int l   = lt0 + row;
        int cglob = QK2 + nh * 64 + cc;              // raw channel base
        const short* rp = reinterpret_cast<const short*>(raw)
                        + (size_t)(b * L_ + l) * QKV_ + cglob;
        short8 cur0 = *reinterpret_cast<const short8*>(rp);
        short8 cur1 = *reinterpret_cast<const short8*>(rp + 8);
        short8 pv0 = {}, pv1 = {};
        if (l > 0) {
            pv0 = *reinterpret_cast<const short8*>(rp - QKV_);
            pv1 = *reinterpret_cast<const short8*>(rp + 8 - QKV_);
        }
        float wa[32];
#pragma unroll
        for (int w4 = 0; w4 < 8; ++w4) {
            float4 wv = *reinterpret_cast<const float4*>(conv_w + cglob * 2 + w4 * 4);
            wa[w4 * 4]     = wv.x; wa[w4 * 4 + 1] = wv.y;
            wa[w4 * 4 + 2] = wv.z; wa[w4 * 4 + 3] = wv.w;
        }
        float dtr = dt[(size_t)bnh * L_ + l];

        short8 vo0, vo1;
#pragma unroll
        for (int j = 0; j < 8; ++j) {
            float u = bfs2f(pv0[j]) * wa[2 * j] + bfs2f(cur0[j]) * wa[2 * j + 1];
            u = fmaxf(u, -80.f);
            float sV = u / (1.f + __expf(-u));
            vo0[j] = f2bfs(sV);
            T[row][cc + j] = f2bfs(sV * dtr);

            float u2 = bfs2f(pv1[j]) * wa[16 + 2 * j] + bfs2f(cur1[j]) * wa[16 + 2 * j + 1];
            u2 = fmaxf(u2, -80.f);
            float sV2 = u2 / (1.f + __expf(-u2));
            vo1[j] = f2bfs(sV2);
            T[row][cc + 8 + j] = f2bfs(sV2 * dtr);
        }
        short* vp = reinterpret_cast<short*>(v)
                  + ((size_t)bnh * L_ + l) * HD_ + cc;
        *reinterpret_cast<short8*>(vp)     = vo0;
        *reinterpret_cast<short8*>(vp + 8) = vo1;
    }
    __syncthreads();
    {
        int d  = tid >> 2;
        int lc = (tid & 3) * 16;
        short8 o0, o1;
#pragma unroll
        for (int j = 0; j < 8; ++j) {
            o0[j] = T[lc + j][d];
            o1[j] = T[lc + 8 + j][d];
        }
        short* dst = reinterpret_cast<short*>(vt)
                   + ((size_t)bnh * HD_ + d) * L_ + lt0 + lc;
        *reinterpret_cast<short8*>(dst)     = o0;
        *reinterpret_cast<short8*>(dst + 8) = o1;
    }
}

// =====================================================================
// quadratic SSD attention — 128-j K staging + hoisted V (round-15 body)
// =====================================================================
__global__ __launch_bounds__(256) void attn_kernel(
    const __hip_bfloat16* __restrict__ q,   // [B,NH,L,HD]
    const __hip_bfloat16* __restrict__ k,   // [B,NH,L,HD]
    const __hip_bfloat16* __restrict__ vt,  // [B,NH,HD,L], dt-scaled
    const float* __restrict__ cs,           // [B,NH,L]
    float* __restrict__ p0,                 // [B,L,DSSM] partials
    float* __restrict__ p1,
    float* __restrict__ p2)
{
    // XCD-grouping decode: 720 = 90 x 8; 6 (b,nh) groups per XCD.
    const int bid  = blockIdx.x;
    const int xcd  = bid & 7;
    const int tq   = bid >> 3;              // 0..89
    const int g    = (tq / 15) * 8 + xcd;   // (b,nh) group 0..47, XCD-pinned
    const int pidx = tq % 15;               // slice 0..14
    const int it   = pIt[pidx];             // 128-row i-tile 0..7
    const int sl   = pSl[pidx];             // partial index 0..2
    const int jt_beg = pJ0[pidx];
    const int b    = g / NH_;
    const int nh   = g % NH_;
    const int tid  = threadIdx.x;
    const int lane = tid & 63;
    const int wave = tid >> 6;
    const int col  = lane & 15;
    const int quad = lane >> 4;
    const int bnh  = b * NH_ + nh;
    const int iw0  = it * 128 + wave * 16;        // group 0 rows
    const int iw1  = iw0 + 64;                    // group 1 rows

    float* pout = (sl == 0) ? p0 : ((sl == 1) ? p1 : p2);

    const short* qp  = reinterpret_cast<const short*>(q);
    const short* kp  = reinterpret_cast<const short*>(k);
    const short* vtp = reinterpret_cast<const short*>(vt);

    __shared__ alignas(16) short Ks[8192];              // 16KB: [half][128][32]
    __shared__ alignas(16) short Ps[4 * 2 * 16 * 72];   // per wave x group
    __shared__ float Cj[384];                           // slice j-window

    const int jbase = jt_beg * 64;
    const int jlim  = min(384, L_ - jbase);
    if (tid < (jlim >> 2))
        *reinterpret_cast<float4*>(&Cj[tid * 4]) =
            *reinterpret_cast<const float4*>(cs + (size_t)bnh * L_ + jbase + tid * 4);

    // Q fragments for both row groups
    const short* qrow0 = qp + ((size_t)bnh * L_ + iw0 + col) * HD_;
    const short* qrow1 = qp + ((size_t)bnh * L_ + iw1 + col) * HD_;
    short8 aq0_0 = *reinterpret_cast<const short8*>(qrow0 + quad * 8);
    short8 aq0_1 = *reinterpret_cast<const short8*>(qrow0 + 32 + quad * 8);
    short8 aq1_0 = *reinterpret_cast<const short8*>(qrow1 + quad * 8);
    short8 aq1_1 = *reinterpret_cast<const short8*>(qrow1 + 32 + quad * 8);

    float csr0[4], csr1[4];
#pragma unroll
    for (int r = 0; r < 4; ++r) {
        csr0[r] = cs[(size_t)bnh * L_ + iw0 + quad * 4 + r];
        csr1[r] = cs[(size_t)bnh * L_ + iw1 + quad * 4 + r];
    }

    // stage 128 K rows: per wave 32 rows x 64ch -> 4 gload_lds
    auto STAGE_K128 = [&](int t128) {
        const short* gk = kp + ((size_t)bnh * L_ + jbase + t128 * 128
                                + wave * 32 + (lane >> 2)) * HD_ + (lane & 3) * 8;
        gload_lds16(gk,                 &Ks[wave * 1024 + lane * 8]);
        gload_lds16(gk + 16 * HD_,      &Ks[wave * 1024 + 512 + lane * 8]);
        gload_lds16(gk + 32,            &Ks[4096 + wave * 1024 + lane * 8]);
        gload_lds16(gk + 16 * HD_ + 32, &Ks[4096 + wave * 1024 + 512 + lane * 8]);
    };

    const int jt_end = min(jt_beg + 5, 2 * it + 1);
    const int n128 = (jt_end - jt_beg + 1) >> 1;   // n64 always even

    STAGE_K128(0);

    floatx4 accO0[4] = {};
    floatx4 accO1[4] = {};

    auto PROCESS = [&](int j0, int h, short8 (&bv)[2][4]) {
#pragma unroll
        for (int s = 0; s < 4; ++s) {
            int jsub = j0 + s * 16;
            short8 bk0 = *reinterpret_cast<const short8*>(
                &Ks[(h * 64 + s * 16 + col) * 32 + quad * 8]);
            short8 bk1 = *reinterpret_cast<const short8*>(
                &Ks[4096 + (h * 64 + s * 16 + col) * 32 + quad * 8]);
            int j = jsub + col;
            float csj = Cj[j - jbase];

            if (jsub <= iw0 + 15) {
                floatx4 sc = {};
                sc = __builtin_amdgcn_mfma_f32_16x16x32_bf16(aq0_0, bk0, sc, 0, 0, 0);
                sc = __builtin_amdgcn_mfma_f32_16x16x32_bf16(aq0_1, bk1, sc, 0, 0, 0);
#pragma unroll
                for (int r = 0; r < 4; ++r) {
                    int i = iw0 + quad * 4 + r;
                    float e = (j <= i) ? __expf(csr0[r] - csj) : 0.f;
                    Ps[wave * 2304 + (quad * 4 + r) * 72 + s * 16 + col] =
                        f2bfs(sc[r] * e);
                }
            } else if (j0 + (s >> 1) * 32 <= iw0 + 15) {
#pragma unroll
                for (int r = 0; r < 4; ++r)
                    Ps[wave * 2304 + (quad * 4 + r) * 72 + s * 16 + col] = 0;
            }

            if (jsub <= iw1 + 15) {
                floatx4 sc = {};
                sc = __builtin_amdgcn_mfma_f32_16x16x32_bf16(aq1_0, bk0, sc, 0, 0, 0);
                sc = __builtin_amdgcn_mfma_f32_16x16x32_bf16(aq1_1, bk1, sc, 0, 0, 0);
#pragma unroll
                for (int r = 0; r < 4; ++r) {
                    int i = iw1 + quad * 4 + r;
                    float e = (j <= i) ? __expf(csr1[r] - csj) : 0.f;
                    Ps[wave * 2304 + 1152 + (quad * 4 + r) * 72 + s * 16 + col] =
                        f2bfs(sc[r] * e);
                }
            } else if (j0 + (s >> 1) * 32 <= iw1 + 15) {
#pragma unroll
                for (int r = 0; r < 4; ++r)
                    Ps[wave * 2304 + 1152 + (quad * 4 + r) * 72 + s * 16 + col] = 0;
            }
        }

#pragma unroll
        for (int c = 0; c < 2; ++c) {
            if (j0 + c * 32 <= iw0 + 15) {
                short8 pa = *reinterpret_cast<const short8*>(
                    &Ps[wave * 2304 + col * 72 + c * 32 + quad * 8]);
#pragma unroll
                for (int nt = 0; nt < 4; ++nt)
                    accO0[nt] = __builtin_amdgcn_mfma_f32_16x16x32_bf16(
                        pa, bv[c][nt], accO0[nt], 0, 0, 0);
            }
            if (j0 + c * 32 <= iw1 + 15) {
                short8 pa = *reinterpret_cast<const short8*>(
                    &Ps[wave * 2304 + 1152 + col * 72 + c * 32 + quad * 8]);
#pragma unroll
                for (int nt = 0; nt < 4; ++nt)
                    accO1[nt] = __builtin_amdgcn_mfma_f32_16x16x32_bf16(
                        pa, bv[c][nt], accO1[nt], 0, 0, 0);
            }
        }
    };

    for (int t = 0; t < n128; ++t) {
        const int j0A = jbase + t * 128;
        const int j0B = j0A + 64;

        // hoist V(A) ABOVE the K drain: V/K latencies overlap
        short8 bvA[2][4];
#pragma unroll
        for (int c = 0; c < 2; ++c) {
            if (j0A + c * 32 <= iw1 + 15) {
#pragma unroll
                for (int nt = 0; nt < 4; ++nt)
                    bvA[c][nt] = *reinterpret_cast<const short8*>(
                        vtp + ((size_t)bnh * HD_ + nt * 16 + col) * L_
                            + j0A + c * 32 + quad * 8);
            }
        }

        asm volatile("s_waitcnt vmcnt(0)" ::: "memory");
        SCHED_;
        __syncthreads();                          // K 128-tile (and Cj) resident

        // V(B) in flight under subtile-A compute
        short8 bvB[2][4];
#pragma unroll
        for (int c = 0; c < 2; ++c) {
            if (j0B + c * 32 <= iw1 + 15) {
#pragma unroll
                for (int nt = 0; nt < 4; ++nt)
                    bvB[c][nt] = *reinterpret_cast<const short8*>(
                        vtp + ((size_t)bnh * HD_ + nt * 16 + col) * L_
                            + j0B + c * 32 + quad * 8);
            }
        }

        PROCESS(j0A, 0, bvA);
        PROCESS(j0B, 1, bvB);

        __syncthreads();                    // all waves done reading Ks
        if (t + 1 < n128) STAGE_K128(t + 1);
    }

#pragma unroll
    for (int nt = 0; nt < 4; ++nt) {
#pragma unroll
        for (int r = 0; r < 4; ++r) {
            int dv = nt * 16 + col;
            int i0 = iw0 + quad * 4 + r;
            int i1 = iw1 + quad * 4 + r;
            pout[((size_t)b * L_ + i0) * DSSM_ + nh * HD_ + dv] = accO0[nt][r];
            pout[((size_t)b * L_ + i1) * DSSM_ + nh * HD_ + dv] = accO1[nt][r];
        }
    }
}

// =====================================================================
// gate: (p0[+p1][+p2] + v*D) * silu(z), then RMSNorm * rms_w  -> bf16
// =====================================================================
__global__ __launch_bounds__(256) void gate_rms_kernel(
    const float* __restrict__ p0,
    const float* __restrict__ p1,
    const float* __restrict__ p2,
    const float* __restrict__ z,
    const __hip_bfloat16* __restrict__ v,   // [B,NH,L,HD]
    const float* __restrict__ Dm,           // [NH,HD]
    const float* __restrict__ rms_w,
    __hip_bfloat16* __restrict__ yn)
{
    int m   = blockIdx.x;           // b*L + l
    int b   = m / L_;
    int l   = m % L_;
    int tid = threadIdx.x;
    size_t base = (size_t)m * DSSM_;
    const bool has1 = (l >= 384);
    const bool has2 = (l >= 768);

    floatx4 acc4[2] = {};
    float ss = 0.f;
#pragma unroll
    for (int t = 0; t < 2; ++t) {
        int i4 = t * 256 + tid;
        if (i4 < DSSM_ / 4) {
            int c  = i4 * 4;
            int nh = c >> 6, d = c & 63;
            floatx4 p = *reinterpret_cast<const floatx4*>(p0 + base + c);
            if (has1) p += *reinterpret_cast<const floatx4*>(p1 + base + c);
            if (has2) p += *reinterpret_cast<const floatx4*>(p2 + base + c);
            floatx4 dm = *reinterpret_cast<const floatx4*>(Dm + c);
            floatx4 zz = *reinterpret_cast<const floatx4*>(z + base + c);
            short4e vv = *reinterpret_cast<const short4e*>(
                reinterpret_cast<const short*>(v)
                + (((size_t)b * NH_ + nh) * L_ + l) * HD_ + d);
            floatx4 g;
#pragma unroll
            for (int j = 0; j < 4; ++j) {
                float yv = p[j] + bfs2f(vv[j]) * dm[j];
                float zv = fmaxf(zz[j], -80.f);
                float gv = yv * (zv / (1.f + __expf(-zv)));
                ss += gv * gv;
                g[j] = gv;
            }
            acc4[t] = g;
        }
    }
#pragma unroll
    for (int off = 32; off; off >>= 1) ss += __shfl_xor(ss, off, 64);
    __shared__ float red[4];
    if ((tid & 63) == 0) red[tid >> 6] = ss;
    __syncthreads();
    ss = red[0] + red[1] + red[2] + red[3];
    float r = rsqrtf(ss / (float)DSSM_ + 1e-6f);
#pragma unroll
    for (int t = 0; t < 2; ++t) {
        int i4 = t * 256 + tid;
        if (i4 < DSSM_ / 4) {
            int c = i4 * 4;
            floatx4 rw = *reinterpret_cast<const floatx4*>(rms_w + c);
            short4e o;
#pragma unroll
            for (int j = 0; j < 4; ++j)
                o[j] = f2bfs(acc4[t][j] * r * rw[j]);
            *reinterpret_cast<short4e*>(
                reinterpret_cast<short*>(yn) + base + c) = o;
        }
    }
}

// =====================================================================
extern "C" void kernel_launch(void* const* d_in, const int* in_sizes, int n_in,
                              void* d_out, int out_size, void* d_ws, size_t ws_size,
                              hipStream_t stream)
{
    const float* x       = (const float*)d_in[0];
    const float* w_qkv   = (const float*)d_in[1];
    const float* conv_w  = (const float*)d_in[2];
    const float* w_dt    = (const float*)d_in[3];
    const float* dt_bias = (const float*)d_in[4];
    const float* a_log   = (const float*)d_in[5];
    const float* Dm      = (const float*)d_in[6];
    const float* w_z     = (const float*)d_in[7];
    const float* b_z     = (const float*)d_in[8];
    const float* rms_w   = (const float*)d_in[9];
    const float* w_o     = (const float*)d_in[10];
    float* out = (float*)d_out;

    char* ws = (char*)d_ws;

    // ---- workspace layout (bytes), total 80,805,888 — overlap-audited ----
    __hip_bfloat16* xb    = (__hip_bfloat16*)(ws);
    __hip_bfloat16* wob   = (__hip_bfloat16*)(ws + 6291456);
    float*          zbuf  = (float*)(ws + 11010048);
    __hip_bfloat16* wcat  = (__hip_bfloat16*)(ws + 23592960);
    __hip_bfloat16* qkvb  = (__hip_bfloat16*)(ws + 42467328);
    __hip_bfloat16* qb    = (__hip_bfloat16*)(ws + 61341696);
    __hip_bfloat16* kb    = (__hip_bfloat16*)(ws + 67633152);
    __hip_bfloat16* vb    = (__hip_bfloat16*)(ws + 73924608);
    float* dt   = (float*)(ws + 80216064);
    float* dA   = (float*)(ws + 80412672);
    float* cs   = (float*)(ws + 80609280);
    // aliases (lifetimes disjoint)
    __hip_bfloat16* vtb = (__hip_bfloat16*)(ws);   // over xb after gemm
    __hip_bfloat16* yn  = (__hip_bfloat16*)(ws);
    float* p0 = (float*)(ws + 23592960);
    float* p1 = (float*)(ws + 36175872);
    float* p2 = (float*)(ws + 48758784);

    // one-time: allow dynamic LDS for the two GEMMs
    static bool attr_set = false;
    if (!attr_set) {
        (void)hipFuncSetAttribute(reinterpret_cast<const void*>(gemm_qkvz_128),
                                  hipFuncAttributeMaxDynamicSharedMemorySize,
                                  81920);
        (void)hipFuncSetAttribute(reinterpret_cast<const void*>(gemm_out_128),
                                  hipFuncAttributeMaxDynamicSharedMemorySize,
                                  57344);
        attr_set = true;
    }

    // 1) weights cast (separate: low-VGPR streaming, full occupancy)
    cast_w_kernel<<<(CN1 + CN2 + CN3) / 1024, 256, 0, stream>>>(
        w_qkv, w_z, w_o, wcat, wob);

    // 2) dtproj + folded x->bf16 cast
    dtproj_kernel<<<M_ / 8, 256, 0, stream>>>(
        x, w_dt, dt_bias, a_log, dt, dA, xb);

    // 3) fused qkv+z GEMM  [2048 x 6144], 128x192 tile, 2 blocks/CU
    gemm_qkvz_128<<<dim3((QKV_ + DSSM_) / 192, M_ / 128), 256, 81920, stream>>>(
        xb, wcat, qkvb, zbuf, b_z);

    // 4) conv (q,k) + conv+transpose (v) + cumsum(dA->cs)
    convvdt_kernel<<<3888, 256, 0, stream>>>(
        qkvb, conv_w, dt, dA, qb, kb, vb, vtb, cs);

    // 5) attention (128-j steps, hoisted V) -> p0/p1/p2
    attn_kernel<<<720, 256, 0, stream>>>(
        qb, kb, vtb, cs, p0, p1, p2);

    // 6) gate + RMSNorm -> yn
    gate_rms_kernel<<<M_, 256, 0, stream>>>(p0, p1, p2, zbuf, vb, Dm, rms_w, yn);

    // 7) out = yn @ w_o^T  (128x96 tile, grid 16x16 = 256 blocks: full chip)
    gemm_out_128<<<dim3(HID_ / 96, M_ / 128), 256, 57344, stream>>>(
        yn, wob, out);
}

// Round 17
// 231.273 us; speedup vs baseline: 1.0957x; 1.0338x over previous
//
#include <hip/hip_runtime.h>
#include <hip/hip_bf16.h>
#include <math.h>

// ---- problem constants ----
#define B_ 2
#define L_ 1024
#define HID_ 1536
#define NH_ 24
#define HD_ 64
#define DSSM_ 1536
#define QKV_ 4608
#define M_ 2048

typedef __attribute__((ext_vector_type(8))) short short8;
typedef __attribute__((ext_vector_type(4))) short short4e;
typedef __attribute__((ext_vector_type(4))) float floatx4;

// async global -> LDS, 16 bytes per lane (global_load_lds_dwordx4)
__device__ __forceinline__ void gload_lds16(const short* g, short* l)
{
    __builtin_amdgcn_global_load_lds(
        (const __attribute__((address_space(1))) void*)g,
        (__attribute__((address_space(3))) void*)l,
        16, 0, 0);
}

__device__ __forceinline__ float bfs2f(short s)
{
    unsigned u = ((unsigned)(unsigned short)s) << 16;
    float f; __builtin_memcpy(&f, &u, 4); return f;
}
__device__ __forceinline__ short f2bfs(float f)
{
    __hip_bfloat16 h = __float2bfloat16(f);
    short s; __builtin_memcpy(&s, &h, 2); return s;
}

// 128-row i-tile slice tables: 15 slices per (b,nh)
__device__ const int pIt[15] = {0,1,2,3,3,4,4,5,5,6,6,6,7,7,7};
__device__ const int pJ0[15] = {0,0,0,0,6,0,6,0,6,0,6,12,0,6,12};
__device__ const int pSl[15] = {0,0,0,0,1,0,1,0,1,0,1,2,0,1,2};

#define CN1 (QKV_ * HID_)     // 7,077,888
#define CN2 (DSSM_ * HID_)    // 2,359,296
#define CN3 (HID_ * DSSM_)    // 2,359,296

#define MFMA_ __builtin_amdgcn_mfma_f32_16x16x32_bf16
#define BAR_() __builtin_amdgcn_s_barrier()
#define SCHED_ __builtin_amdgcn_sched_barrier(0)

// =====================================================================
// weights cast — 8 elems/thread (32B loads, 16B bf16 stores; guideline
// 13 store-side vectorization).  Segment boundaries are multiples of 8.
// =====================================================================
__global__ void cast_w_kernel(
    const float* __restrict__ wq,
    const float* __restrict__ wz, const float* __restrict__ wo,
    __hip_bfloat16* __restrict__ wcat,   // [QKV+DSSM, HID]
    __hip_bfloat16* __restrict__ wob)
{
    int i = (blockIdx.x * 256 + threadIdx.x) * 8;
    const float* src; __hip_bfloat16* dst; int off;
    if (i < CN1)             { src = wq; dst = wcat;       off = i; }
    else if (i < CN1 + CN2)  { src = wz; dst = wcat + CN1; off = i - CN1; }
    else                     { src = wo; dst = wob;        off = i - CN1 - CN2; }
    float4 f0 = *reinterpret_cast<const float4*>(src + off);
    float4 f1 = *reinterpret_cast<const float4*>(src + off + 4);
    short8 o8;
    o8[0] = f2bfs(f0.x); o8[1] = f2bfs(f0.y); o8[2] = f2bfs(f0.z); o8[3] = f2bfs(f0.w);
    o8[4] = f2bfs(f1.x); o8[5] = f2bfs(f1.y); o8[6] = f2bfs(f1.z); o8[7] = f2bfs(f1.w);
    *reinterpret_cast<short8*>(reinterpret_cast<short*>(dst) + off) = o8;
}

// =====================================================================
// dt projection + folded x->bf16 cast (256 blocks, high VGPR ok here)
// =====================================================================
__global__ __launch_bounds__(256) void dtproj_kernel(
    const float* __restrict__ x,        // [B*L, HID]
    const float* __restrict__ w_dt,     // [NH, HID]
    const float* __restrict__ dt_bias,  // [NH]
    const float* __restrict__ a_log,    // [NH]
    float* __restrict__ dt,             // [B*NH, L]
    float* __restrict__ dA,
    __hip_bfloat16* __restrict__ xb)    // [B*L, HID] bf16
{
    const int tid  = threadIdx.x;
    const int wave = tid >> 6;
    const int lane = tid & 63;
    const int m0   = blockIdx.x * 8 + wave * 2;   // rows m0, m0+1

    float4 xa[2][6];
#pragma unroll
    for (int rr = 0; rr < 2; ++rr)
#pragma unroll
        for (int j = 0; j < 6; ++j)
            xa[rr][j] = *reinterpret_cast<const float4*>(
                x + (size_t)(m0 + rr) * HID_ + lane * 4 + j * 256);

    short* xbp = reinterpret_cast<short*>(xb);
#pragma unroll
    for (int rr = 0; rr < 2; ++rr)
#pragma unroll
        for (int j = 0; j < 6; ++j) {
            short4e ov;
            ov[0] = f2bfs(xa[rr][j].x); ov[1] = f2bfs(xa[rr][j].y);
            ov[2] = f2bfs(xa[rr][j].z); ov[3] = f2bfs(xa[rr][j].w);
            *reinterpret_cast<short4e*>(
                xbp + (size_t)(m0 + rr) * HID_ + lane * 4 + j * 256) = ov;
        }

    float acc0[NH_], acc1[NH_];
#pragma unroll
    for (int n = 0; n < NH_; ++n) {
        float s0 = 0.f, s1 = 0.f;
#pragma unroll
        for (int j = 0; j < 6; ++j) {
            float4 w = *reinterpret_cast<const float4*>(
                w_dt + (size_t)n * HID_ + lane * 4 + j * 256);
            s0 += xa[0][j].x * w.x + xa[0][j].y * w.y
                + xa[0][j].z * w.z + xa[0][j].w * w.w;
            s1 += xa[1][j].x * w.x + xa[1][j].y * w.y
                + xa[1][j].z * w.z + xa[1][j].w * w.w;
        }
        acc0[n] = s0;
        acc1[n] = s1;
    }

#pragma unroll
    for (int off = 32; off; off >>= 1) {
#pragma unroll
        for (int n = 0; n < NH_; ++n) {
            acc0[n] += __shfl_xor(acc0[n], off, 64);
            acc1[n] += __shfl_xor(acc1[n], off, 64);
        }
    }

    if (lane < NH_) {
        const int n = lane;
        float bias = dt_bias[n];
        float Aval = -__expf(a_log[n]);
        float v0 = acc0[n] + bias;
        float v1 = acc1[n] + bias;
        v0 = (v0 > 20.f) ? v0 : log1pf(__expf(v0));
        v1 = (v1 > 20.f) ? v1 : log1pf(__expf(v1));
        int b0 = m0 / L_, l0 = m0 % L_;
        size_t o0 = ((size_t)b0 * NH_ + n) * L_ + l0;
        dt[o0]     = v0;
        dA[o0]     = v0 * Aval;
        dt[o0 + 1] = v1;
        dA[o0 + 1] = v1 * Aval;
    }
}

// =====================================================================
// Fused qkv+z GEMM: 128x192 tile / BK=64 / 4 waves, 2 blocks/CU
// =====================================================================
#define CSTR 200   // epilogue C-LDS row stride (shorts): 400B, 16B-aligned

__global__ __launch_bounds__(256, 2) void gemm_qkvz_128(
    const __hip_bfloat16* __restrict__ A,
    const __hip_bfloat16* __restrict__ Bm,
    __hip_bfloat16* __restrict__ qkv_out,
    float* __restrict__ z_out,
    const float* __restrict__ b_z)
{
    extern __shared__ short lds[];
    const int K  = HID_;
    const int NT = K / 64;                 // 24 K-tiles
    const int tid   = threadIdx.x;
    const int lane  = tid & 63;
    const int wave  = tid >> 6;
    const int col16 = lane & 15;
    const int quad  = lane >> 4;
    const int wm = wave >> 1;              // 0..1  (M half, 64 rows)
    const int wn = wave & 1;               // 0..1  (N half, 96 cols)
    const int rowblk = blockIdx.y * 128;
    const int colblk = blockIdx.x * 192;

    const short* Ap = reinterpret_cast<const short*>(A);
    const short* Bp = reinterpret_cast<const short*>(Bm);

    const int o  = tid * 16;                         // byte off in 4KB unit
    const int s  = o ^ (((o >> 7) & 7) << 4);
    const int sr = s >> 7;                           // row 0..31 within unit
    const int sc = (s & 127) >> 1;                   // short col 0..63

    const int mask = (col16 & 7) << 4;
    const int e0 = ((quad * 16)      ^ mask) >> 1;   // kk=0
    const int e1 = ((64 + quad * 16) ^ mask) >> 1;   // kk=1
    const int arow = (wm * 64 + col16) * 64;         // + m*1024
    const int brow = (wn * 96 + col16) * 64;         // + n*1024

    floatx4 acc[4][6] = {};

    auto STAGE_ALL = [&](int c, int t) {   // 10 gload_lds: full tile t
        const short* ga = Ap + (size_t)(rowblk + sr) * K + t * 64 + sc;
        short* da = &lds[c * 8192 + tid * 8];
#pragma unroll
        for (int u = 0; u < 4; ++u)
            gload_lds16(ga + (size_t)(u * 32) * K, da + u * 2048);
        const short* gb = Bp + (size_t)(colblk + sr) * K + t * 64 + sc;
        short* db = &lds[16384 + c * 12288 + tid * 8];
#pragma unroll
        for (int u = 0; u < 6; ++u)
            gload_lds16(gb + (size_t)(u * 32) * K, db + u * 2048);
    };

    STAGE_ALL(0, 0);
    asm volatile("s_waitcnt vmcnt(0)" ::: "memory");
    SCHED_;
    BAR_();

    for (int t = 0; t < NT; ++t) {
        const int cur = t & 1;
        if (t + 1 < NT) STAGE_ALL(cur ^ 1, t + 1);

        const int Ab = cur * 8192;
        const int Bb = 16384 + cur * 12288;
        short8 af0[4], af1[4], bf0[6], bf1[6];
#pragma unroll
        for (int m = 0; m < 4; ++m) {
            af0[m] = *reinterpret_cast<const short8*>(&lds[Ab + arow + m * 1024 + e0]);
            af1[m] = *reinterpret_cast<const short8*>(&lds[Ab + arow + m * 1024 + e1]);
        }
#pragma unroll
        for (int n = 0; n < 6; ++n) {
            bf0[n] = *reinterpret_cast<const short8*>(&lds[Bb + brow + n * 1024 + e0]);
            bf1[n] = *reinterpret_cast<const short8*>(&lds[Bb + brow + n * 1024 + e1]);
        }
        asm volatile("s_waitcnt lgkmcnt(0)" ::: "memory");
        SCHED_;

        __builtin_amdgcn_s_setprio(1);
#pragma unroll
        for (int m = 0; m < 4; ++m)
#pragma unroll
            for (int n = 0; n < 6; ++n) {
                acc[m][n] = MFMA_(af0[m], bf0[n], acc[m][n], 0, 0, 0);
                acc[m][n] = MFMA_(af1[m], bf1[n], acc[m][n], 0, 0, 0);
            }
        __builtin_amdgcn_s_setprio(0);

        asm volatile("s_waitcnt vmcnt(0)" ::: "memory");
        SCHED_;
        BAR_();
    }

    // ---- epilogue ----
    if (blockIdx.x < 24) {
        const int rb = wm * 64 + quad * 4;
        const int cb = wn * 96 + col16;
#pragma unroll
        for (int m = 0; m < 4; ++m)
#pragma unroll
            for (int n = 0; n < 6; ++n)
#pragma unroll
                for (int r = 0; r < 4; ++r)
                    lds[(rb + m * 16 + r) * CSTR + cb + n * 16] =
                        f2bfs(acc[m][n][r]);
        __syncthreads();
        const int row = tid >> 1;          // 0..127
        const int seg = tid & 1;
        const short* srcp = &lds[row * CSTR + seg * 96];
        short* dstp = reinterpret_cast<short*>(qkv_out)
                    + (size_t)(rowblk + row) * QKV_ + colblk + seg * 96;
#pragma unroll
        for (int j = 0; j < 12; ++j)
            *reinterpret_cast<short8*>(dstp + j * 8) =
                *reinterpret_cast<const short8*>(srcp + j * 8);
    } else {
        const int row0  = rowblk + wm * 64;
        const int col0g = colblk + wn * 96 - QKV_;
#pragma unroll
        for (int m = 0; m < 4; ++m)
#pragma unroll
            for (int n = 0; n < 6; ++n)
#pragma unroll
                for (int r = 0; r < 4; ++r) {
                    int row = row0 + m * 16 + quad * 4 + r;
                    int col = col0g + n * 16 + col16;
                    z_out[(size_t)row * DSSM_ + col] = acc[m][n][r] + b_z[col];
                }
    }
}

// =====================================================================
// Output GEMM: out[M,HID] = yn[M,DSSM] @ wob[HID,DSSM]^T
// 128x96 tile / BK=64 / 4 waves; grid 16x16 = 256 blocks (full chip).
// =====================================================================
__global__ __launch_bounds__(256, 2) void gemm_out_128(
    const __hip_bfloat16* __restrict__ A,
    const __hip_bfloat16* __restrict__ Bm,
    float* __restrict__ Co)
{
    extern __shared__ short lds[];
    const int K  = DSSM_;
    const int NT = K / 64;                 // 24 K-tiles
    const int tid   = threadIdx.x;
    const int lane  = tid & 63;
    const int wave  = tid >> 6;
    const int col16 = lane & 15;
    const int quad  = lane >> 4;
    const int wm = wave >> 1;              // 0..1  (M half, 64 rows)
    const int wn = wave & 1;               // 0..1  (N half, 48 cols)
    const int rowblk = blockIdx.y * 128;
    const int colblk = blockIdx.x * 96;

    const short* Ap = reinterpret_cast<const short*>(A);
    const short* Bp = reinterpret_cast<const short*>(Bm);

    const int o  = tid * 16;                         // byte off in 4KB unit
    const int s  = o ^ (((o >> 7) & 7) << 4);
    const int sr = s >> 7;                           // row 0..31 within unit
    const int sc = (s & 127) >> 1;                   // short col 0..63

    const int mask = (col16 & 7) << 4;
    const int e0 = ((quad * 16)      ^ mask) >> 1;   // kk=0
    const int e1 = ((64 + quad * 16) ^ mask) >> 1;   // kk=1
    const int arow = (wm * 64 + col16) * 64;         // + m*1024
    const int brow = (wn * 48 + col16) * 64;         // + n*1024

    floatx4 acc[4][3] = {};

    auto STAGE_ALL = [&](int c, int t) {   // 7 gload_lds: full tile t
        const short* ga = Ap + (size_t)(rowblk + sr) * K + t * 64 + sc;
        short* da = &lds[c * 8192 + tid * 8];
#pragma unroll
        for (int u = 0; u < 4; ++u)
            gload_lds16(ga + (size_t)(u * 32) * K, da + u * 2048);
        const short* gb = Bp + (size_t)(colblk + sr) * K + t * 64 + sc;
        short* db = &lds[16384 + c * 6144 + tid * 8];
#pragma unroll
        for (int u = 0; u < 3; ++u)
            gload_lds16(gb + (size_t)(u * 32) * K, db + u * 2048);
    };

    STAGE_ALL(0, 0);
    asm volatile("s_waitcnt vmcnt(0)" ::: "memory");
    SCHED_;
    BAR_();

    for (int t = 0; t < NT; ++t) {
        const int cur = t & 1;
        if (t + 1 < NT) STAGE_ALL(cur ^ 1, t + 1);

        const int Ab = cur * 8192;
        const int Bb = 16384 + cur * 6144;
        short8 af0[4], af1[4], bf0[3], bf1[3];
#pragma unroll
        for (int m = 0; m < 4; ++m) {
            af0[m] = *reinterpret_cast<const short8*>(&lds[Ab + arow + m * 1024 + e0]);
            af1[m] = *reinterpret_cast<const short8*>(&lds[Ab + arow + m * 1024 + e1]);
        }
#pragma unroll
        for (int n = 0; n < 3; ++n) {
            bf0[n] = *reinterpret_cast<const short8*>(&lds[Bb + brow + n * 1024 + e0]);
            bf1[n] = *reinterpret_cast<const short8*>(&lds[Bb + brow + n * 1024 + e1]);
        }
        asm volatile("s_waitcnt lgkmcnt(0)" ::: "memory");
        SCHED_;

        __builtin_amdgcn_s_setprio(1);
#pragma unroll
        for (int m = 0; m < 4; ++m)
#pragma unroll
            for (int n = 0; n < 3; ++n) {
                acc[m][n] = MFMA_(af0[m], bf0[n], acc[m][n], 0, 0, 0);
                acc[m][n] = MFMA_(af1[m], bf1[n], acc[m][n], 0, 0, 0);
            }
        __builtin_amdgcn_s_setprio(0);

        asm volatile("s_waitcnt vmcnt(0)" ::: "memory");
        SCHED_;
        BAR_();
    }

    // ---- epilogue: fp32 direct stores ----
    const int row0 = rowblk + wm * 64;
    const int col0 = colblk + wn * 48;
#pragma unroll
    for (int m = 0; m < 4; ++m)
#pragma unroll
        for (int n = 0; n < 3; ++n)
#pragma unroll
            for (int r = 0; r < 4; ++r) {
                int row = row0 + m * 16 + quad * 4 + r;
                int col = col0 + n * 16 + col16;
                Co[(size_t)row * HID_ + col] = acc[m][n][r];
            }
}

// =====================================================================
// conv+vdt+cumsum fused:
//   blocks [0,3072)      = q/k conv (8 ch/thread)
//   blocks [3072,3840)   = v conv + silu + v write + dt-scale + transpose
//   blocks [3840,3888)   = cumsum dA -> cs (one (b,nh) per block)
// =====================================================================
#define QK2 (2 * DSSM_)   // 3072

__global__ __launch_bounds__(256) void convvdt_kernel(
    const __hip_bfloat16* __restrict__ raw,
    const float* __restrict__ conv_w,
    const float* __restrict__ dt,           // [B*NH, L]
    const float* __restrict__ dA,           // [B*NH, L]
    __hip_bfloat16* __restrict__ q,
    __hip_bfloat16* __restrict__ k,
    __hip_bfloat16* __restrict__ v,
    __hip_bfloat16* __restrict__ vt,        // [B,NH,HD,L], dt-scaled
    float* __restrict__ cs)                 // [B*NH, L]
{
    __shared__ short T[64][72];
    __shared__ float red4[4];
    const int tid = threadIdx.x;

    if (blockIdx.x >= 3840) {
        // ---- part C: cumsum of dA row -> cs (256-thread scan, 4/thread)
        const int bnh  = blockIdx.x - 3840;          // 0..47
        const int lane = tid & 63;
        const int wave = tid >> 6;
        float4 dv = *reinterpret_cast<const float4*>(dA + (size_t)bnh * L_ + tid * 4);
        float s1 = dv.x + dv.y;
        float s2 = s1 + dv.z;
        float s3 = s2 + dv.w;
        float tot = s3;
        float sc = tot;
#pragma unroll
        for (int off = 1; off < 64; off <<= 1) {
            float o2 = __shfl_up(sc, off, 64);
            if (lane >= off) sc += o2;
        }
        if (lane == 63) red4[wave] = sc;
        __syncthreads();
        float woff = 0.f;
#pragma unroll
        for (int w = 0; w < 4; ++w)
            if (w < wave) woff += red4[w];
        float base = woff + sc - tot;
        float* dst = cs + (size_t)bnh * L_ + tid * 4;
        dst[0] = base + dv.x;
        dst[1] = base + s1;
        dst[2] = base + s2;
        dst[3] = base + s3;
        return;
    }

    if (blockIdx.x < 3072) {
        // ---- part A: q/k conv ----
        int idx8 = blockIdx.x * 256 + tid;          // over B*L*QK2/8
        int c8 = (idx8 % (QK2 / 8)) * 8;
        int ml = idx8 / (QK2 / 8);
        int l  = ml % L_;
        int b  = ml / L_;

        const short* base = reinterpret_cast<const short*>(raw) + (size_t)ml * QKV_ + c8;
        short8 curv = *reinterpret_cast<const short8*>(base);
        short8 prevv = {};
        if (l > 0) prevv = *reinterpret_cast<const short8*>(base - QKV_);

        float4 w0 = *reinterpret_cast<const float4*>(conv_w + c8 * 2);
        float4 w1 = *reinterpret_cast<const float4*>(conv_w + c8 * 2 + 4);
        float4 w2 = *reinterpret_cast<const float4*>(conv_w + c8 * 2 + 8);
        float4 w3 = *reinterpret_cast<const float4*>(conv_w + c8 * 2 + 12);
        const float wa[16] = {w0.x, w0.y, w0.z, w0.w, w1.x, w1.y, w1.z, w1.w,
                              w2.x, w2.y, w2.z, w2.w, w3.x, w3.y, w3.z, w3.w};

        short8 outv;
#pragma unroll
        for (int j = 0; j < 8; ++j) {
            float u = bfs2f(prevv[j]) * wa[2 * j] + bfs2f(curv[j]) * wa[2 * j + 1];
            u = fmaxf(u, -80.f);
            outv[j] = f2bfs(u / (1.f + __expf(-u)));
        }

        int part = c8 / DSSM_;
        int cc   = c8 % DSSM_;
        int nh   = cc >> 6;
        int d    = cc & 63;
        __hip_bfloat16* dst = (part == 0) ? q : k;
        *reinterpret_cast<short8*>(
            reinterpret_cast<short*>(dst) + (((size_t)b * NH_ + nh) * L_ + l) * HD_ + d)
            = outv;
        return;
    }

    // ---- part B: v conv + write v + transpose (dt-scaled) -> vt ----
    const int bid2 = blockIdx.x - 3072;             // 0..767
    const int lt0 = (bid2 & 15) * 64;
    const int nh  = (bid2 >> 4) % NH_;
    const int b   = bid2 / (16 * NH_);
    const int bnh = b * NH_ + nh;

    {
        int row = tid >> 2;                          // 0..63
        int cc  = (tid & 3) * 16;                    // 0,16,32,48
        int l   = lt0 + row;
        int cglob = QK2 + nh * 64 + cc;              // raw channel base
        const short* rp = reinterpret_cast<const short*>(raw)
                        + (size_t)(b * L_ + l) * QKV_ + cglob;
        short8 cur0 = *reinterpret_cast<const short8*>(rp);
        short8 cur1 = *reinterpret_cast<const short8*>(rp + 8);
        short8 pv0 = {}, pv1 = {};
        if (l > 0) {
            pv0 = *reinterpret_cast<const short8*>(rp - QKV_);
            pv1 = *reinterpret_cast<const short8*>(rp + 8 - QKV_);
        }
        float wa[32];
#pragma unroll
        for (int w4 = 0; w4 < 8; ++w4) {
            float4 wv = *reinterpret_cast<const float4*>(conv_w + cglob * 2 + w4 * 4);
            wa[w4 * 4]     = wv.x; wa[w4 * 4 + 1] = wv.y;
            wa[w4 * 4 + 2] = wv.z; wa[w4 * 4 + 3] = wv.w;
        }
        float dtr = dt[(size_t)bnh * L_ + l];

        short8 vo0, vo1;
#pragma unroll
        for (int j = 0; j < 8; ++j) {
            float u = bfs2f(pv0[j]) * wa[2 * j] + bfs2f(cur0[j]) * wa[2 * j + 1];
            u = fmaxf(u, -80.f);
            float sV = u / (1.f + __expf(-u));
            vo0[j] = f2bfs(sV);
            T[row][cc + j] = f2bfs(sV * dtr);

            float u2 = bfs2f(pv1[j]) * wa[16 + 2 * j] + bfs2f(cur1[j]) * wa[16 + 2 * j + 1];
            u2 = fmaxf(u2, -80.f);
            float sV2 = u2 / (1.f + __expf(-u2));
            vo1[j] = f2bfs(sV2);
            T[row][cc + 8 + j] = f2bfs(sV2 * dtr);
        }
        short* vp = reinterpret_cast<short*>(v)
                  + ((size_t)bnh * L_ + l) * HD_ + cc;
        *reinterpret_cast<short8*>(vp)     = vo0;
        *reinterpret_cast<short8*>(vp + 8) = vo1;
    }
    __syncthreads();
    {
        int d  = tid >> 2;
        int lc = (tid & 3) * 16;
        short8 o0, o1;
#pragma unroll
        for (int j = 0; j < 8; ++j) {
            o0[j] = T[lc + j][d];
            o1[j] = T[lc + 8 + j][d];
        }
        short* dst = reinterpret_cast<short*>(vt)
                   + ((size_t)bnh * HD_ + d) * L_ + lt0 + lc;
        *reinterpret_cast<short8*>(dst)     = o0;
        *reinterpret_cast<short8*>(dst + 8) = o1;
    }
}

// =====================================================================
// quadratic SSD attention — 128-j K staging + hoisted V
// =====================================================================
__global__ __launch_bounds__(256) void attn_kernel(
    const __hip_bfloat16* __restrict__ q,   // [B,NH,L,HD]
    const __hip_bfloat16* __restrict__ k,   // [B,NH,L,HD]
    const __hip_bfloat16* __restrict__ vt,  // [B,NH,HD,L], dt-scaled
    const float* __restrict__ cs,           // [B,NH,L]
    float* __restrict__ p0,                 // [B,L,DSSM] partials
    float* __restrict__ p1,
    float* __restrict__ p2)
{
    // XCD-grouping decode: 720 = 90 x 8; 6 (b,nh) groups per XCD.
    const int bid  = blockIdx.x;
    const int xcd  = bid & 7;
    const int tq   = bid >> 3;              // 0..89
    const int g    = (tq / 15) * 8 + xcd;   // (b,nh) group 0..47, XCD-pinned
    const int pidx = tq % 15;               // slice 0..14
    const int it   = pIt[pidx];             // 128-row i-tile 0..7
    const int sl   = pSl[pidx];             // partial index 0..2
    const int jt_beg = pJ0[pidx];
    const int b    = g / NH_;
    const int nh   = g % NH_;
    const int tid  = threadIdx.x;
    const int lane = tid & 63;
    const int wave = tid >> 6;
    const int col  = lane & 15;
    const int quad = lane >> 4;
    const int bnh  = b * NH_ + nh;
    const int iw0  = it * 128 + wave * 16;        // group 0 rows
    const int iw1  = iw0 + 64;                    // group 1 rows

    float* pout = (sl == 0) ? p0 : ((sl == 1) ? p1 : p2);

    const short* qp  = reinterpret_cast<const short*>(q);
    const short* kp  = reinterpret_cast<const short*>(k);
    const short* vtp = reinterpret_cast<const short*>(vt);

    __shared__ alignas(16) short Ks[8192];              // 16KB: [half][128][32]
    __shared__ alignas(16) short Ps[4 * 2 * 16 * 72];   // per wave x group
    __shared__ float Cj[384];                           // slice j-window

    const int jbase = jt_beg * 64;
    const int jlim  = min(384, L_ - jbase);
    if (tid < (jlim >> 2))
        *reinterpret_cast<float4*>(&Cj[tid * 4]) =
            *reinterpret_cast<const float4*>(cs + (size_t)bnh * L_ + jbase + tid * 4);

    // Q fragments for both row groups
    const short* qrow0 = qp + ((size_t)bnh * L_ + iw0 + col) * HD_;
    const short* qrow1 = qp + ((size_t)bnh * L_ + iw1 + col) * HD_;
    short8 aq0_0 = *reinterpret_cast<const short8*>(qrow0 + quad * 8);
    short8 aq0_1 = *reinterpret_cast<const short8*>(qrow0 + 32 + quad * 8);
    short8 aq1_0 = *reinterpret_cast<const short8*>(qrow1 + quad * 8);
    short8 aq1_1 = *reinterpret_cast<const short8*>(qrow1 + 32 + quad * 8);

    float csr0[4], csr1[4];
#pragma unroll
    for (int r = 0; r < 4; ++r) {
        csr0[r] = cs[(size_t)bnh * L_ + iw0 + quad * 4 + r];
        csr1[r] = cs[(size_t)bnh * L_ + iw1 + quad * 4 + r];
    }

    // stage 128 K rows: per wave 32 rows x 64ch -> 4 gload_lds
    auto STAGE_K128 = [&](int t128) {
        const short* gk = kp + ((size_t)bnh * L_ + jbase + t128 * 128
                                + wave * 32 + (lane >> 2)) * HD_ + (lane & 3) * 8;
        gload_lds16(gk,                 &Ks[wave * 1024 + lane * 8]);
        gload_lds16(gk + 16 * HD_,      &Ks[wave * 1024 + 512 + lane * 8]);
        gload_lds16(gk + 32,            &Ks[4096 + wave * 1024 + lane * 8]);
        gload_lds16(gk + 16 * HD_ + 32, &Ks[4096 + wave * 1024 + 512 + lane * 8]);
    };

    const int jt_end = min(jt_beg + 5, 2 * it + 1);
    const int n128 = (jt_end - jt_beg + 1) >> 1;   // n64 always even

    STAGE_K128(0);

    floatx4 accO0[4] = {};
    floatx4 accO1[4] = {};

    auto PROCESS = [&](int j0, int h, short8 (&bv)[2][4]) {
#pragma unroll
        for (int s = 0; s < 4; ++s) {
            int jsub = j0 + s * 16;
            short8 bk0 = *reinterpret_cast<const short8*>(
                &Ks[(h * 64 + s * 16 + col) * 32 + quad * 8]);
            short8 bk1 = *reinterpret_cast<const short8*>(
                &Ks[4096 + (h * 64 + s * 16 + col) * 32 + quad * 8]);
            int j = jsub + col;
            float csj = Cj[j - jbase];

            if (jsub <= iw0 + 15) {
                floatx4 sc = {};
                sc = __builtin_amdgcn_mfma_f32_16x16x32_bf16(aq0_0, bk0, sc, 0, 0, 0);
                sc = __builtin_amdgcn_mfma_f32_16x16x32_bf16(aq0_1, bk1, sc, 0, 0, 0);
#pragma unroll
                for (int r = 0; r < 4; ++r) {
                    int i = iw0 + quad * 4 + r;
                    float e = (j <= i) ? __expf(csr0[r] - csj) : 0.f;
                    Ps[wave * 2304 + (quad * 4 + r) * 72 + s * 16 + col] =
                        f2bfs(sc[r] * e);
                }
            } else if (j0 + (s >> 1) * 32 <= iw0 + 15) {
#pragma unroll
                for (int r = 0; r < 4; ++r)
                    Ps[wave * 2304 + (quad * 4 + r) * 72 + s * 16 + col] = 0;
            }

            if (jsub <= iw1 + 15) {
                floatx4 sc = {};
                sc = __builtin_amdgcn_mfma_f32_16x16x32_bf16(aq1_0, bk0, sc, 0, 0, 0);
                sc = __builtin_amdgcn_mfma_f32_16x16x32_bf16(aq1_1, bk1, sc, 0, 0, 0);
#pragma unroll
                for (int r = 0; r < 4; ++r) {
                    int i = iw1 + quad * 4 + r;
                    float e = (j <= i) ? __expf(csr1[r] - csj) : 0.f;
                    Ps[wave * 2304 + 1152 + (quad * 4 + r) * 72 + s * 16 + col] =
                        f2bfs(sc[r] * e);
                }
            } else if (j0 + (s >> 1) * 32 <= iw1 + 15) {
#pragma unroll
                for (int r = 0; r < 4; ++r)
                    Ps[wave * 2304 + 1152 + (quad * 4 + r) * 72 + s * 16 + col] = 0;
            }
        }

#pragma unroll
        for (int c = 0; c < 2; ++c) {
            if (j0 + c * 32 <= iw0 + 15) {
                short8 pa = *reinterpret_cast<const short8*>(
                    &Ps[wave * 2304 + col * 72 + c * 32 + quad * 8]);
#pragma unroll
                for (int nt = 0; nt < 4; ++nt)
                    accO0[nt] = __builtin_amdgcn_mfma_f32_16x16x32_bf16(
                        pa, bv[c][nt], accO0[nt], 0, 0, 0);
            }
            if (j0 + c * 32 <= iw1 + 15) {
                short8 pa = *reinterpret_cast<const short8*>(
                    &Ps[wave * 2304 + 1152 + col * 72 + c * 32 + quad * 8]);
#pragma unroll
                for (int nt = 0; nt < 4; ++nt)
                    accO1[nt] = __builtin_amdgcn_mfma_f32_16x16x32_bf16(
                        pa, bv[c][nt], accO1[nt], 0, 0, 0);
            }
        }
    };

    for (int t = 0; t < n128; ++t) {
        const int j0A = jbase + t * 128;
        const int j0B = j0A + 64;

        // hoist V(A) ABOVE the K drain: V/K latencies overlap
        short8 bvA[2][4];
#pragma unroll
        for (int c = 0; c < 2; ++c) {
            if (j0A + c * 32 <= iw1 + 15) {
#pragma unroll
                for (int nt = 0; nt < 4; ++nt)
                    bvA[c][nt] = *reinterpret_cast<const short8*>(
                        vtp + ((size_t)bnh * HD_ + nt * 16 + col) * L_
                            + j0A + c * 32 + quad * 8);
            }
        }

        asm volatile("s_waitcnt vmcnt(0)" ::: "memory");
        SCHED_;
        __syncthreads();                          // K 128-tile (and Cj) resident

        // V(B) in flight under subtile-A compute
        short8 bvB[2][4];
#pragma unroll
        for (int c = 0; c < 2; ++c) {
            if (j0B + c * 32 <= iw1 + 15) {
#pragma unroll
                for (int nt = 0; nt < 4; ++nt)
                    bvB[c][nt] = *reinterpret_cast<const short8*>(
                        vtp + ((size_t)bnh * HD_ + nt * 16 + col) * L_
                            + j0B + c * 32 + quad * 8);
            }
        }

        PROCESS(j0A, 0, bvA);
        PROCESS(j0B, 1, bvB);

        __syncthreads();                    // all waves done reading Ks
        if (t + 1 < n128) STAGE_K128(t + 1);
    }

#pragma unroll
    for (int nt = 0; nt < 4; ++nt) {
#pragma unroll
        for (int r = 0; r < 4; ++r) {
            int dv = nt * 16 + col;
            int i0 = iw0 + quad * 4 + r;
            int i1 = iw1 + quad * 4 + r;
            pout[((size_t)b * L_ + i0) * DSSM_ + nh * HD_ + dv] = accO0[nt][r];
            pout[((size_t)b * L_ + i1) * DSSM_ + nh * HD_ + dv] = accO1[nt][r];
        }
    }
}

// =====================================================================
// gate: (p0[+p1][+p2] + v*D) * silu(z), then RMSNorm * rms_w  -> bf16
// =====================================================================
__global__ __launch_bounds__(256) void gate_rms_kernel(
    const float* __restrict__ p0,
    const float* __restrict__ p1,
    const float* __restrict__ p2,
    const float* __restrict__ z,
    const __hip_bfloat16* __restrict__ v,   // [B,NH,L,HD]
    const float* __restrict__ Dm,           // [NH,HD]
    const float* __restrict__ rms_w,
    __hip_bfloat16* __restrict__ yn)
{
    int m   = blockIdx.x;           // b*L + l
    int b   = m / L_;
    int l   = m % L_;
    int tid = threadIdx.x;
    size_t base = (size_t)m * DSSM_;
    const bool has1 = (l >= 384);
    const bool has2 = (l >= 768);

    floatx4 acc4[2] = {};
    float ss = 0.f;
#pragma unroll
    for (int t = 0; t < 2; ++t) {
        int i4 = t * 256 + tid;
        if (i4 < DSSM_ / 4) {
            int c  = i4 * 4;
            int nh = c >> 6, d = c & 63;
            floatx4 p = *reinterpret_cast<const floatx4*>(p0 + base + c);
            if (has1) p += *reinterpret_cast<const floatx4*>(p1 + base + c);
            if (has2) p += *reinterpret_cast<const floatx4*>(p2 + base + c);
            floatx4 dm = *reinterpret_cast<const floatx4*>(Dm + c);
            floatx4 zz = *reinterpret_cast<const floatx4*>(z + base + c);
            short4e vv = *reinterpret_cast<const short4e*>(
                reinterpret_cast<const short*>(v)
                + (((size_t)b * NH_ + nh) * L_ + l) * HD_ + d);
            floatx4 g;
#pragma unroll
            for (int j = 0; j < 4; ++j) {
                float yv = p[j] + bfs2f(vv[j]) * dm[j];
                float zv = fmaxf(zz[j], -80.f);
                float gv = yv * (zv / (1.f + __expf(-zv)));
                ss += gv * gv;
                g[j] = gv;
            }
            acc4[t] = g;
        }
    }
#pragma unroll
    for (int off = 32; off; off >>= 1) ss += __shfl_xor(ss, off, 64);
    __shared__ float red[4];
    if ((tid & 63) == 0) red[tid >> 6] = ss;
    __syncthreads();
    ss = red[0] + red[1] + red[2] + red[3];
    float r = rsqrtf(ss / (float)DSSM_ + 1e-6f);
#pragma unroll
    for (int t = 0; t < 2; ++t) {
        int i4 = t * 256 + tid;
        if (i4 < DSSM_ / 4) {
            int c = i4 * 4;
            floatx4 rw = *reinterpret_cast<const floatx4*>(rms_w + c);
            short4e o;
#pragma unroll
            for (int j = 0; j < 4; ++j)
                o[j] = f2bfs(acc4[t][j] * r * rw[j]);
            *reinterpret_cast<short4e*>(
                reinterpret_cast<short*>(yn) + base + c) = o;
        }
    }
}

// =====================================================================
extern "C" void kernel_launch(void* const* d_in, const int* in_sizes, int n_in,
                              void* d_out, int out_size, void* d_ws, size_t ws_size,
                              hipStream_t stream)
{
    const float* x       = (const float*)d_in[0];
    const float* w_qkv   = (const float*)d_in[1];
    const float* conv_w  = (const float*)d_in[2];
    const float* w_dt    = (const float*)d_in[3];
    const float* dt_bias = (const float*)d_in[4];
    const float* a_log   = (const float*)d_in[5];
    const float* Dm      = (const float*)d_in[6];
    const float* w_z     = (const float*)d_in[7];
    const float* b_z     = (const float*)d_in[8];
    const float* rms_w   = (const float*)d_in[9];
    const float* w_o     = (const float*)d_in[10];
    float* out = (float*)d_out;

    char* ws = (char*)d_ws;

    // ---- workspace layout (bytes), total 80,805,888 — overlap-audited ----
    __hip_bfloat16* xb    = (__hip_bfloat16*)(ws);
    __hip_bfloat16* wob   = (__hip_bfloat16*)(ws + 6291456);
    float*          zbuf  = (float*)(ws + 11010048);
    __hip_bfloat16* wcat  = (__hip_bfloat16*)(ws + 23592960);
    __hip_bfloat16* qkvb  = (__hip_bfloat16*)(ws + 42467328);
    __hip_bfloat16* qb    = (__hip_bfloat16*)(ws + 61341696);
    __hip_bfloat16* kb    = (__hip_bfloat16*)(ws + 67633152);
    __hip_bfloat16* vb    = (__hip_bfloat16*)(ws + 73924608);
    float* dt   = (float*)(ws + 80216064);
    float* dA   = (float*)(ws + 80412672);
    float* cs   = (float*)(ws + 80609280);
    // aliases (lifetimes disjoint)
    __hip_bfloat16* vtb = (__hip_bfloat16*)(ws);   // over xb after gemm
    __hip_bfloat16* yn  = (__hip_bfloat16*)(ws);
    float* p0 = (float*)(ws + 23592960);
    float* p1 = (float*)(ws + 36175872);
    float* p2 = (float*)(ws + 48758784);

    // one-time: allow dynamic LDS for the two GEMMs
    static bool attr_set = false;
    if (!attr_set) {
        (void)hipFuncSetAttribute(reinterpret_cast<const void*>(gemm_qkvz_128),
                                  hipFuncAttributeMaxDynamicSharedMemorySize,
                                  81920);
        (void)hipFuncSetAttribute(reinterpret_cast<const void*>(gemm_out_128),
                                  hipFuncAttributeMaxDynamicSharedMemorySize,
                                  57344);
        attr_set = true;
    }

    // 1) weights cast (8 elems/thread: 32B loads, 16B stores)
    cast_w_kernel<<<(CN1 + CN2 + CN3) / 2048, 256, 0, stream>>>(
        w_qkv, w_z, w_o, wcat, wob);

    // 2) dtproj + folded x->bf16 cast
    dtproj_kernel<<<M_ / 8, 256, 0, stream>>>(
        x, w_dt, dt_bias, a_log, dt, dA, xb);

    // 3) fused qkv+z GEMM  [2048 x 6144], 128x192 tile, 2 blocks/CU
    gemm_qkvz_128<<<dim3((QKV_ + DSSM_) / 192, M_ / 128), 256, 81920, stream>>>(
        xb, wcat, qkvb, zbuf, b_z);

    // 4) conv (q,k) + conv+transpose (v) + cumsum(dA->cs)
    convvdt_kernel<<<3888, 256, 0, stream>>>(
        qkvb, conv_w, dt, dA, qb, kb, vb, vtb, cs);

    // 5) attention (128-j steps, hoisted V) -> p0/p1/p2
    attn_kernel<<<720, 256, 0, stream>>>(
        qb, kb, vtb, cs, p0, p1, p2);

    // 6) gate + RMSNorm -> yn
    gate_rms_kernel<<<M_, 256, 0, stream>>>(p0, p1, p2, zbuf, vb, Dm, rms_w, yn);

    // 7) out = yn @ w_o^T  (128x96 tile, grid 16x16 = 256 blocks: full chip)
    gemm_out_128<<<dim3(HID_ / 96, M_ / 128), 256, 57344, stream>>>(
        yn, wob, out);
}